// Round 4
// baseline (219.259 us; speedup 1.0000x reference)
//
#include <hip/hip_runtime.h>
#include <hip/hip_bf16.h>
#include <math.h>

// Problem constants (from reference)
constexpr int B_ = 8, Q_ = 900;
constexpr int S_ = 13294;
constexpr int BQ = 7200;     // B*Q
constexpr int BS = 106352;   // B*S

typedef __bf16 bf16x8 __attribute__((ext_vector_type(8)));
typedef float  f32x4  __attribute__((ext_vector_type(4)));

// ---------------------------------------------------------------------------
// Fused transpose+cast of all weights into bf16 [N][K=256] layouts.
// bi 0..63: w_q -> tq | 64..127: w_v -> tv | 128..191: w_o -> to
// 192..255: w_off2 -> toff2 | 256..383: [w_ax | w_ay | w_off1(:256)] -> tcat[512][256]
// ---------------------------------------------------------------------------
__global__ __launch_bounds__(256)
void transpose_all(const float* __restrict__ wq, const float* __restrict__ wv,
                   const float* __restrict__ wo, const float* __restrict__ woff1,
                   const float* __restrict__ woff2, const float* __restrict__ wax,
                   const float* __restrict__ way,
                   __bf16* __restrict__ tq, __bf16* __restrict__ tv,
                   __bf16* __restrict__ to_, __bf16* __restrict__ toff2,
                   __bf16* __restrict__ tcat)
{
    const int bi = blockIdx.x;
    __shared__ float tile[32][33];
    const int tx = threadIdx.x & 31, ty = threadIdx.x >> 5;

    const float* src; __bf16* dst; int k0, n0, scol, sN = 256;
    if (bi < 256) {
        const int wid = bi >> 6, t = bi & 63;
        k0 = (t & 7) * 32; n0 = (t >> 3) * 32; scol = n0;
        if      (wid == 0) { src = wq;    dst = tq;    }
        else if (wid == 1) { src = wv;    dst = tv;    }
        else if (wid == 2) { src = wo;    dst = to_;   }
        else               { src = woff2; dst = toff2; }
    } else {
        const int t = bi - 256;             // 0..127
        k0 = (t & 7) * 32; n0 = (t >> 3) * 32;   // n0 0..480
        dst = tcat;
        if      (n0 < 128) { src = wax;   scol = n0;       sN = 128; }
        else if (n0 < 256) { src = way;   scol = n0 - 128; sN = 128; }
        else               { src = woff1; scol = n0 - 256; sN = 256; }
    }

    #pragma unroll
    for (int i = 0; i < 4; ++i)
        tile[ty + 8 * i][tx] = src[(size_t)(k0 + ty + 8 * i) * sN + scol + tx];
    __syncthreads();
    #pragma unroll
    for (int i = 0; i < 4; ++i)
        dst[(size_t)(n0 + ty + 8 * i) * 256 + k0 + tx] = (__bf16)tile[tx][ty + 8 * i];
}

// ---------------------------------------------------------------------------
// Barrier-free register GEMM: each wave computes a 64x64 output tile.
// C[M,N] = A[M,K=256](f32, LDA) @ Wt[N,256](bf16) + bias, K fully unrolled,
// fragments loaded DIRECTLY from global (no LDS, no __syncthreads).
// A-frag: lane l -> row = l&15, k = (l>>4)*8 + j (two float4 loads, cvt->bf16)
// B-frag: lane l -> col = l&15, same k (one 16B bf16x8 load)
// C/D   : col = l&15, row = (l>>4)*4 + reg
// BIASMODE 0: bias0[col]. 1 (cat): <128 bias0, <256 bias1[c-128], else bias2[c-256]
// RELUHI: cols>=256 get rank-2 extra update (obj rows of w_off1) + relu.
// ---------------------------------------------------------------------------
template<int BIASMODE, bool RELUHI, bool OUTBF16>
__global__ __launch_bounds__(256, 3)
void gemm_reg(const float* __restrict__ A, const __bf16* __restrict__ Wt,
              const float* __restrict__ bias0, const float* __restrict__ bias1,
              const float* __restrict__ bias2, const float* __restrict__ extra,
              const float* __restrict__ Wex, void* __restrict__ outp,
              int M, int N, int LDA, int tiles_n)
{
    const int wid  = (blockIdx.x << 2) + (threadIdx.x >> 6);
    const int lane = threadIdx.x & 63;
    const int tile_m = wid / tiles_n, tile_n = wid - tile_m * tiles_n;
    const int row0 = tile_m * 64, col0 = tile_n * 64;
    if (row0 >= M) return;
    const int l15 = lane & 15, l4 = lane >> 4;

    const float*  ap[4];
    const __bf16* bp[4];
    #pragma unroll
    for (int mi = 0; mi < 4; ++mi) {
        const int r = min(row0 + mi * 16 + l15, M - 1);
        ap[mi] = A + (size_t)r * LDA + l4 * 8;
    }
    #pragma unroll
    for (int ni = 0; ni < 4; ++ni) {
        const int c = col0 + ni * 16 + l15;
        bp[ni] = Wt + (size_t)c * 256 + l4 * 8;
    }

    f32x4 acc[4][4] = {};

    float4 a0[4], a1[4]; bf16x8 bfr[4];
    #pragma unroll
    for (int mi = 0; mi < 4; ++mi) {
        a0[mi] = *(const float4*)(ap[mi]);
        a1[mi] = *(const float4*)(ap[mi] + 4);
    }
    #pragma unroll
    for (int ni = 0; ni < 4; ++ni) bfr[ni] = *(const bf16x8*)(bp[ni]);

    #pragma unroll
    for (int kk = 0; kk < 8; ++kk) {
        float4 na0[4], na1[4]; bf16x8 nb[4];
        if (kk < 7) {
            #pragma unroll
            for (int mi = 0; mi < 4; ++mi) {
                ap[mi] += 32;
                na0[mi] = *(const float4*)(ap[mi]);
                na1[mi] = *(const float4*)(ap[mi] + 4);
            }
            #pragma unroll
            for (int ni = 0; ni < 4; ++ni) {
                bp[ni] += 32;
                nb[ni] = *(const bf16x8*)(bp[ni]);
            }
        }
        bf16x8 am[4];
        #pragma unroll
        for (int mi = 0; mi < 4; ++mi) {
            am[mi][0] = (__bf16)a0[mi].x; am[mi][1] = (__bf16)a0[mi].y;
            am[mi][2] = (__bf16)a0[mi].z; am[mi][3] = (__bf16)a0[mi].w;
            am[mi][4] = (__bf16)a1[mi].x; am[mi][5] = (__bf16)a1[mi].y;
            am[mi][6] = (__bf16)a1[mi].z; am[mi][7] = (__bf16)a1[mi].w;
        }
        #pragma unroll
        for (int mi = 0; mi < 4; ++mi)
            #pragma unroll
            for (int ni = 0; ni < 4; ++ni)
                acc[mi][ni] = __builtin_amdgcn_mfma_f32_16x16x32_bf16(
                    am[mi], bfr[ni], acc[mi][ni], 0, 0, 0);
        if (kk < 7) {
            #pragma unroll
            for (int mi = 0; mi < 4; ++mi) { a0[mi] = na0[mi]; a1[mi] = na1[mi]; }
            #pragma unroll
            for (int ni = 0; ni < 4; ++ni) bfr[ni] = nb[ni];
        }
    }

    // epilogue
    int   colb[4];
    float bb[4], we0[4], we1[4];
    #pragma unroll
    for (int ni = 0; ni < 4; ++ni) {
        const int c = col0 + ni * 16 + l15;
        colb[ni] = c;
        if (BIASMODE == 0) bb[ni] = bias0[c];
        else bb[ni] = (c < 128) ? bias0[c] : (c < 256 ? bias1[c - 128] : bias2[c - 256]);
        if (RELUHI && c >= 256) { we0[ni] = Wex[c - 256]; we1[ni] = Wex[c - 256 + 256]; }
        else                    { we0[ni] = 0.f; we1[ni] = 0.f; }
    }
    #pragma unroll
    for (int mi = 0; mi < 4; ++mi) {
        #pragma unroll
        for (int rr = 0; rr < 4; ++rr) {
            const int row = row0 + mi * 16 + l4 * 4 + rr;
            if (row >= M) continue;
            float e0 = 0.f, e1 = 0.f;
            if (RELUHI) { e0 = extra[(size_t)row * 2]; e1 = extra[(size_t)row * 2 + 1]; }
            #pragma unroll
            for (int ni = 0; ni < 4; ++ni) {
                float v = acc[mi][ni][rr] + bb[ni];
                if (RELUHI && colb[ni] >= 256) {
                    v += e0 * we0[ni] + e1 * we1[ni];
                    v = fmaxf(v, 0.f);
                }
                if (OUTBF16) ((__bf16*)outp)[(size_t)row * N + colb[ni]] = (__bf16)v;
                else         ((float*)outp)[(size_t)row * N + colb[ni]]  = v;
            }
        }
    }
}

// ---------------------------------------------------------------------------
// Fused: softmax (spec cancels: constant along softmax axis) + locations +
// bilinear sampling + aggregation. One block per (b,q), 256 threads.
// axyhid layout: row stride 512 = [ax(128) | ay(128) | hid(256)]
// ---------------------------------------------------------------------------
__device__ __forceinline__
float corner_val_bf(const __bf16* __restrict__ vb, int st, int Hl, int Wl,
                    int xi, int yi, float w, int hd)
{
    const bool valid = (xi >= 0) & (xi < Wl) & (yi >= 0) & (yi < Hl);
    const int idx = min(max(yi, 0), Hl - 1) * Wl + min(max(xi, 0), Wl - 1);
    const float g = (float)vb[(size_t)(st + idx) * 256 + hd];
    return valid ? g * w : 0.f;
}

__global__ __launch_bounds__(256)
void attn_sample_kernel(const float* __restrict__ axyhid,
                        const float* __restrict__ refp, const float* __restrict__ objs,
                        const float* __restrict__ off, const __bf16* __restrict__ v,
                        float* __restrict__ agg)
{
    const int bq = blockIdx.x;
    const int b  = bq / Q_;
    const int tid = threadIdx.x;

    __shared__ float sm[128];
    __shared__ float sa[128];
    __shared__ float sl[256];

    if (tid < 128)
        sm[tid] = axyhid[(size_t)bq * 512 + tid] * axyhid[(size_t)bq * 512 + 128 + tid];
    __syncthreads();

    if (tid < 128) {
        const int h = tid >> 4;
        float mx = -1e30f;
        #pragma unroll
        for (int i = 0; i < 16; ++i) mx = fmaxf(mx, sm[h * 16 + i]);
        float s = 0.f;
        #pragma unroll
        for (int i = 0; i < 16; ++i) s += __expf(sm[h * 16 + i] - mx);
        sa[tid] = __expf(sm[tid] - mx) / s;

        const int l = (tid >> 2) & 3;
        const float os0 = objs[(size_t)bq * 2], os1 = objs[(size_t)bq * 2 + 1];
        const float r0 = refp[((size_t)bq * 4 + l) * 2];
        const float r1 = refp[((size_t)bq * 4 + l) * 2 + 1];
        const float o0 = off[(size_t)bq * 256 + tid * 2]     * os0;
        const float o1 = off[(size_t)bq * 256 + tid * 2 + 1] * os1;
        sl[tid * 2]     = fminf(fmaxf(r0 + o0, 0.f), 1.f);
        sl[tid * 2 + 1] = fminf(fmaxf(r1 + o1, 0.f), 1.f);
    }
    __syncthreads();

    const int h = tid >> 5, d = tid & 31;
    const int hd = h * 32 + d;
    const __bf16* vb = v + (size_t)b * S_ * 256;

    const int Hl_arr[4] = {100, 50, 25, 13};
    const int Wl_arr[4] = {100, 50, 25, 13};
    const int st_arr[4] = {0, 10000, 12500, 13125};

    float acc = 0.f;
    #pragma unroll
    for (int lvl = 0; lvl < 4; ++lvl) {
        const int Hl = Hl_arr[lvl], Wl = Wl_arr[lvl], st = st_arr[lvl];
        #pragma unroll
        for (int p = 0; p < 4; ++p) {
            const int li = (h * 4 + lvl) * 4 + p;
            const float lx = sl[li * 2], ly = sl[li * 2 + 1];
            const float a  = sa[li];
            const float x = lx * (float)Wl - 0.5f;
            const float y = ly * (float)Hl - 0.5f;
            const float x0f = floorf(x), y0f = floorf(y);
            const float fx = x - x0f, fy = y - y0f;
            const int x0 = (int)x0f, y0 = (int)y0f;
            const float w00 = (1.f - fx) * (1.f - fy);
            const float w10 = fx * (1.f - fy);
            const float w01 = (1.f - fx) * fy;
            const float w11 = fx * fy;
            float s = 0.f;
            s += corner_val_bf(vb, st, Hl, Wl, x0,     y0,     w00, hd);
            s += corner_val_bf(vb, st, Hl, Wl, x0 + 1, y0,     w10, hd);
            s += corner_val_bf(vb, st, Hl, Wl, x0,     y0 + 1, w01, hd);
            s += corner_val_bf(vb, st, Hl, Wl, x0 + 1, y0 + 1, w11, hd);
            acc += a * s;
        }
    }
    agg[(size_t)bq * 256 + tid] = acc;
}

// ---------------------------------------------------------------------------
extern "C" void kernel_launch(void* const* d_in, const int* in_sizes, int n_in,
                              void* d_out, int out_size, void* d_ws, size_t ws_size,
                              hipStream_t stream)
{
    const float* query = (const float*)d_in[0];
    const float* refp  = (const float*)d_in[1];
    const float* x_in  = (const float*)d_in[2];
    const float* objs  = (const float*)d_in[3];
    const float* w_q    = (const float*)d_in[6];
    const float* b_q    = (const float*)d_in[7];
    const float* w_v    = (const float*)d_in[8];
    const float* b_v    = (const float*)d_in[9];
    const float* w_o    = (const float*)d_in[10];
    const float* b_o    = (const float*)d_in[11];
    const float* w_off1 = (const float*)d_in[12];
    const float* b_off1 = (const float*)d_in[13];
    const float* w_off2 = (const float*)d_in[14];
    const float* b_off2 = (const float*)d_in[15];
    const float* w_ax   = (const float*)d_in[16];
    const float* b_ax   = (const float*)d_in[17];
    const float* w_ay   = (const float*)d_in[18];
    const float* b_ay   = (const float*)d_in[19];

    float* ws = (float*)d_ws;
    float* q_ws      = ws;                               // BQ*256 f32
    float* axyhid_ws = q_ws      + (size_t)BQ * 256;     // BQ*512 f32
    float* off_ws    = axyhid_ws + (size_t)BQ * 512;     // BQ*256 f32
    float* agg_ws    = off_ws    + (size_t)BQ * 256;     // BQ*256 f32
    __bf16* v_bf   = (__bf16*)(agg_ws + (size_t)BQ * 256);   // BS*256 bf16
    __bf16* wt_q    = v_bf    + (size_t)BS * 256;
    __bf16* wt_v    = wt_q    + 256 * 256;
    __bf16* wt_o    = wt_v    + 256 * 256;
    __bf16* wt_off2 = wt_o    + 256 * 256;
    __bf16* wt_cat  = wt_off2 + 256 * 256;               // 512*256

    const dim3 blk(256);

    // weight prep
    transpose_all<<<384, blk, 0, stream>>>(w_q, w_v, w_o, w_off1, w_off2, w_ax, w_ay,
                                           wt_q, wt_v, wt_o, wt_off2, wt_cat);

    // q = query @ w_q + b_q -> f32   (113 row-tiles x 4 col-tiles)
    gemm_reg<0, false, false><<<113, blk, 0, stream>>>(
        query, wt_q, b_q, nullptr, nullptr, nullptr, nullptr, q_ws,
        BQ, 256, 256, 4);

    // [ax|ay|hid] = q @ [w_ax|w_ay|w_off1] (+bias cat, +obj rank-2 & relu on hid)
    gemm_reg<1, true, false><<<226, blk, 0, stream>>>(
        q_ws, wt_cat, b_ax, b_ay, b_off1, objs, w_off1 + 256 * 256, axyhid_ws,
        BQ, 512, 256, 8);

    // offsets = hid @ w_off2 + b_off2 -> f32
    gemm_reg<0, false, false><<<113, blk, 0, stream>>>(
        axyhid_ws + 256, wt_off2, b_off2, nullptr, nullptr, nullptr, nullptr, off_ws,
        BQ, 256, 512, 4);

    // v = x_in @ w_v + b_v -> bf16   (1662 row-tiles x 4)
    gemm_reg<0, false, true><<<1662, blk, 0, stream>>>(
        x_in, wt_v, b_v, nullptr, nullptr, nullptr, nullptr, v_bf,
        BS, 256, 256, 4);

    // fused softmax/locs/sampling (spec cancels in softmax — dropped exactly)
    attn_sample_kernel<<<BQ, blk, 0, stream>>>(axyhid_ws, refp, objs, off_ws,
                                               v_bf, agg_ws);

    // out = agg @ w_o + b_o -> f32
    gemm_reg<0, false, false><<<113, blk, 0, stream>>>(
        agg_ws, wt_o, b_o, nullptr, nullptr, nullptr, nullptr, (float*)d_out,
        BQ, 256, 256, 4);
}

// Round 7
// 162.040 us; speedup vs baseline: 1.3531x; 1.3531x over previous
//
#include <hip/hip_runtime.h>
#include <hip/hip_bf16.h>
#include <math.h>

// Problem constants (from reference)
constexpr int B_ = 8, Q_ = 900;
constexpr int S_ = 13294;
constexpr int BQ = 7200;     // B*Q
constexpr int BS = 106352;   // B*S

typedef __bf16 bf16x8 __attribute__((ext_vector_type(8)));
typedef float  f32x4  __attribute__((ext_vector_type(4)));

__device__ __forceinline__ void load_lds16(const void* g, void* lds) {
    __builtin_amdgcn_global_load_lds(
        (const __attribute__((address_space(1))) void*)g,
        (__attribute__((address_space(3))) void*)lds, 16, 0, 0);
}

// ---------------------------------------------------------------------------
// Fused transpose+cast of weights into bf16 [N][K=256] layouts.
// bi 0..63: w_v -> tv | 64..127: w_o -> to | 128..191: w_off2 -> toff2
// 192..319: [w_ax | w_ay | w_off1(:256)] -> tcat[512][256]
// ---------------------------------------------------------------------------
__global__ __launch_bounds__(256)
void transpose_all(const float* __restrict__ wv, const float* __restrict__ wo,
                   const float* __restrict__ woff1, const float* __restrict__ woff2,
                   const float* __restrict__ wax, const float* __restrict__ way,
                   __bf16* __restrict__ tv, __bf16* __restrict__ to_,
                   __bf16* __restrict__ toff2, __bf16* __restrict__ tcat)
{
    const int bi = blockIdx.x;
    __shared__ float tile[32][33];
    const int tx = threadIdx.x & 31, ty = threadIdx.x >> 5;

    const float* src; __bf16* dst; int k0, n0, scol, sN = 256;
    if (bi < 192) {
        const int wid = bi >> 6, t = bi & 63;
        k0 = (t & 7) * 32; n0 = (t >> 3) * 32; scol = n0;
        if      (wid == 0) { src = wv;    dst = tv;    }
        else if (wid == 1) { src = wo;    dst = to_;   }
        else               { src = woff2; dst = toff2; }
    } else {
        const int t = bi - 192;                  // 0..127
        k0 = (t & 7) * 32; n0 = (t >> 3) * 32;   // n0 0..480
        dst = tcat;
        if      (n0 < 128) { src = wax;   scol = n0;       sN = 128; }
        else if (n0 < 256) { src = way;   scol = n0 - 128; sN = 128; }
        else               { src = woff1; scol = n0 - 256; sN = 256; }
    }

    #pragma unroll
    for (int i = 0; i < 4; ++i)
        tile[ty + 8 * i][tx] = src[(size_t)(k0 + ty + 8 * i) * sN + scol + tx];
    __syncthreads();
    #pragma unroll
    for (int i = 0; i < 4; ++i)
        dst[(size_t)(n0 + ty + 8 * i) * 256 + k0 + tx] = (__bf16)tile[tx][ty + 8 * i];
}

// ---------------------------------------------------------------------------
// Wcomb[n][k] = sum_c tcat[n][c] * wq[k][c]   (512x256x256, bf16 out)
// tcat: bf16 [512][256]; wq: ORIGINAL row-major f32 (wq[k][c] = Wq[k,c]).
// D[n][k] = sum_c tcat[n][c]*wq[k][c] = (Wq @ Wcat)[k][n] — the [N][K] layout.
// ---------------------------------------------------------------------------
__global__ __launch_bounds__(256)
void combine_w(const __bf16* __restrict__ tcat, const float* __restrict__ wq,
               __bf16* __restrict__ wcomb)
{
    const int wid  = (blockIdx.x << 2) + (threadIdx.x >> 6);
    const int lane = threadIdx.x & 63;
    const int n0 = (wid >> 2) * 64, k0 = (wid & 3) * 64;
    const int l15 = lane & 15, l4 = lane >> 4;

    f32x4 acc[4][4] = {};
    #pragma unroll
    for (int s = 0; s < 8; ++s) {
        const int c0 = s * 32 + l4 * 8;
        bf16x8 am[4], bm[4];
        #pragma unroll
        for (int mi = 0; mi < 4; ++mi)
            am[mi] = *(const bf16x8*)(tcat + (size_t)(n0 + mi * 16 + l15) * 256 + c0);
        #pragma unroll
        for (int ni = 0; ni < 4; ++ni) {
            const float* wr_ = wq + (size_t)(k0 + ni * 16 + l15) * 256 + c0;
            const float4 f0 = ((const float4*)wr_)[0];
            const float4 f1 = ((const float4*)wr_)[1];
            bm[ni][0] = (__bf16)f0.x; bm[ni][1] = (__bf16)f0.y;
            bm[ni][2] = (__bf16)f0.z; bm[ni][3] = (__bf16)f0.w;
            bm[ni][4] = (__bf16)f1.x; bm[ni][5] = (__bf16)f1.y;
            bm[ni][6] = (__bf16)f1.z; bm[ni][7] = (__bf16)f1.w;
        }
        #pragma unroll
        for (int mi = 0; mi < 4; ++mi)
            #pragma unroll
            for (int ni = 0; ni < 4; ++ni)
                acc[mi][ni] = __builtin_amdgcn_mfma_f32_16x16x32_bf16(
                    am[mi], bm[ni], acc[mi][ni], 0, 0, 0);
    }
    #pragma unroll
    for (int mi = 0; mi < 4; ++mi)
        #pragma unroll
        for (int rr = 0; rr < 4; ++rr) {
            const int n = n0 + mi * 16 + l4 * 4 + rr;
            #pragma unroll
            for (int ni = 0; ni < 4; ++ni)
                wcomb[(size_t)n * 256 + k0 + ni * 16 + l15] = (__bf16)acc[mi][ni][rr];
        }
}

// bcomb[n] = sum_c b_q[c]*tcat[n][c] + (n<128? b_ax[n] : n<256? b_ay[n-128] : b_off1[n-256])
__global__ __launch_bounds__(256)
void combine_bias(const __bf16* __restrict__ tcat, const float* __restrict__ bq,
                  const float* __restrict__ bax, const float* __restrict__ bay,
                  const float* __restrict__ boff1, float* __restrict__ bcomb)
{
    const int n = blockIdx.x * 256 + threadIdx.x;
    float acc = (n < 128) ? bax[n] : (n < 256 ? bay[n - 128] : boff1[n - 256]);
    const __bf16* row = tcat + (size_t)n * 256;
    for (int c = 0; c < 256; ++c) acc += bq[c] * (float)row[c];
    bcomb[n] = acc;
}

// ---------------------------------------------------------------------------
// bf16 MFMA GEMM — R3-VERIFIED structure (2-phase reg prefetch, __syncthreads)
// C[M,N] = A[M,K=256](f32,LDA) @ Wt[N,256](bf16) + bias -> f32/bf16
// BM=BN=128, BK=32, 4 waves (2x2), 64x64/wave, mfma_f32_16x16x32_bf16.
// A: reg-staged (prefetch f32 loads early, cvt+swizzled ds_write after MFMA)
// B: global_load_lds w/ source-side XOR swizzle (linear LDS dest).
// RELUHI: cols>=256 get rank-2 obj update (w_off1 extra rows) + relu.
// LDS declared as float4 arrays -> guaranteed 16B alignment.
// ---------------------------------------------------------------------------
template<bool RELUHI, bool OUTBF16>
__global__ __launch_bounds__(256)
void gemm_bf16(const float* __restrict__ A, const __bf16* __restrict__ Wt,
               const float* __restrict__ bias, const float* __restrict__ extra,
               const float* __restrict__ Wex, void* __restrict__ outp,
               int M, int N, int LDA)
{
    __shared__ float4 AsbV[2][512];   // 2 x 8KB
    __shared__ float4 BsbV[2][512];   // 2 x 8KB
    char* const Asb_b = (char*)AsbV;
    char* const Bsb_b = (char*)BsbV;

    const int tid  = threadIdx.x;
    const int wave = tid >> 6, lane = tid & 63;
    const int wr = wave >> 1, wc = wave & 1;
    const int row0 = blockIdx.y * 128, col0 = blockIdx.x * 128;
    const int l15 = lane & 15, l4 = lane >> 4;

    // A staging: thread t -> row=t>>1, k-half=t&1 (16 f32 each)
    const int st_row = tid >> 1, st_kh = tid & 1;
    const int gr_cl  = min(row0 + st_row, M - 1);
    const float* Abase = A + (size_t)gr_cl * LDA + st_kh * 16;
    const int asw   = (st_row >> 1) & 3;
    const int a_wo0 = st_row * 64 + ((st_kh * 2)     ^ asw) * 16;
    const int a_wo1 = st_row * 64 + ((st_kh * 2 + 1) ^ asw) * 16;

    // fragment read offsets (bytes within one buffer)
    int a_off[4], b_off[4];
    #pragma unroll
    for (int mi = 0; mi < 4; ++mi) {
        const int r   = wr * 64 + mi * 16 + l15;
        const int kcp = l4 ^ ((r >> 1) & 3);
        a_off[mi] = r * 64 + kcp * 16;
    }
    #pragma unroll
    for (int ni = 0; ni < 4; ++ni) {
        const int c   = wc * 64 + ni * 16 + l15;
        const int kcp = l4 ^ ((c >> 1) & 3);
        b_off[ni] = c * 64 + kcp * 16;
    }

    // B staging mapping (R3-verified source-side swizzle)
    const __bf16* bsrc[2];
    #pragma unroll
    for (int i = 0; i < 2; ++i) {
        const int c   = (wave * 2 + i) * 64 + lane;
        const int col = c >> 2, kcp = c & 3;
        const int kc  = kcp ^ ((col >> 1) & 3);
        bsrc[i] = Wt + (size_t)(col0 + col) * 256 + kc * 8;
    }

    auto issueB = [&](int kt, int buf) {
        #pragma unroll
        for (int i = 0; i < 2; ++i)
            load_lds16(bsrc[i] + kt * 32, Bsb_b + buf * 8192 + (wave * 2 + i) * 1024);
    };
    auto writeA = [&](int buf, float4 f0, float4 f1, float4 f2, float4 f3) {
        bf16x8 c0, c1;
        c0[0] = (__bf16)f0.x; c0[1] = (__bf16)f0.y; c0[2] = (__bf16)f0.z; c0[3] = (__bf16)f0.w;
        c0[4] = (__bf16)f1.x; c0[5] = (__bf16)f1.y; c0[6] = (__bf16)f1.z; c0[7] = (__bf16)f1.w;
        c1[0] = (__bf16)f2.x; c1[1] = (__bf16)f2.y; c1[2] = (__bf16)f2.z; c1[3] = (__bf16)f2.w;
        c1[4] = (__bf16)f3.x; c1[5] = (__bf16)f3.y; c1[6] = (__bf16)f3.z; c1[7] = (__bf16)f3.w;
        *(bf16x8*)(Asb_b + buf * 8192 + a_wo0) = c0;
        *(bf16x8*)(Asb_b + buf * 8192 + a_wo1) = c1;
    };

    f32x4 acc[4][4] = {};
    const int nk = 8;   // K = 256, BK = 32

    // prologue: stage tile 0
    {
        issueB(0, 0);
        const float4 f0 = ((const float4*)Abase)[0];
        const float4 f1 = ((const float4*)Abase)[1];
        const float4 f2 = ((const float4*)Abase)[2];
        const float4 f3 = ((const float4*)Abase)[3];
        writeA(0, f0, f1, f2, f3);
    }
    __syncthreads();

    int buf = 0;
    for (int kt = 0; kt < nk - 1; ++kt) {
        // prefetch tile kt+1 (loads fly while we compute tile kt)
        const float* ga = Abase + (kt + 1) * 32;
        const float4 g0 = ((const float4*)ga)[0];
        const float4 g1 = ((const float4*)ga)[1];
        const float4 g2 = ((const float4*)ga)[2];
        const float4 g3 = ((const float4*)ga)[3];
        issueB(kt + 1, buf ^ 1);

        bf16x8 a[4], b[4];
        #pragma unroll
        for (int mi = 0; mi < 4; ++mi) a[mi] = *(const bf16x8*)(Asb_b + buf * 8192 + a_off[mi]);
        #pragma unroll
        for (int ni = 0; ni < 4; ++ni) b[ni] = *(const bf16x8*)(Bsb_b + buf * 8192 + b_off[ni]);
        #pragma unroll
        for (int mi = 0; mi < 4; ++mi)
            #pragma unroll
            for (int ni = 0; ni < 4; ++ni)
                acc[mi][ni] = __builtin_amdgcn_mfma_f32_16x16x32_bf16(
                    a[mi], b[ni], acc[mi][ni], 0, 0, 0);

        writeA(buf ^ 1, g0, g1, g2, g3);
        __syncthreads();
        buf ^= 1;
    }

    // final tile compute
    {
        bf16x8 a[4], b[4];
        #pragma unroll
        for (int mi = 0; mi < 4; ++mi) a[mi] = *(const bf16x8*)(Asb_b + buf * 8192 + a_off[mi]);
        #pragma unroll
        for (int ni = 0; ni < 4; ++ni) b[ni] = *(const bf16x8*)(Bsb_b + buf * 8192 + b_off[ni]);
        #pragma unroll
        for (int mi = 0; mi < 4; ++mi)
            #pragma unroll
            for (int ni = 0; ni < 4; ++ni)
                acc[mi][ni] = __builtin_amdgcn_mfma_f32_16x16x32_bf16(
                    a[mi], b[ni], acc[mi][ni], 0, 0, 0);
    }

    // epilogue (RELUHI variant verified in R4's gemm_reg)
    int   colb[4];
    float bb[4], we0[4], we1[4];
    #pragma unroll
    for (int ni = 0; ni < 4; ++ni) {
        const int c = col0 + wc * 64 + ni * 16 + l15;
        colb[ni] = c;
        bb[ni]   = bias[c];
        if (RELUHI && c >= 256) { we0[ni] = Wex[c - 256]; we1[ni] = Wex[c - 256 + 256]; }
        else                    { we0[ni] = 0.f; we1[ni] = 0.f; }
    }
    #pragma unroll
    for (int mi = 0; mi < 4; ++mi) {
        #pragma unroll
        for (int rr = 0; rr < 4; ++rr) {
            const int row = row0 + wr * 64 + mi * 16 + l4 * 4 + rr;
            if (row >= M) continue;
            float e0 = 0.f, e1 = 0.f;
            if (RELUHI) { e0 = extra[(size_t)row * 2]; e1 = extra[(size_t)row * 2 + 1]; }
            #pragma unroll
            for (int ni = 0; ni < 4; ++ni) {
                float v = acc[mi][ni][rr] + bb[ni];
                if (RELUHI && colb[ni] >= 256) {
                    v += e0 * we0[ni] + e1 * we1[ni];
                    v = fmaxf(v, 0.f);
                }
                if (OUTBF16) ((__bf16*)outp)[(size_t)row * N + colb[ni]] = (__bf16)v;
                else         ((float*)outp)[(size_t)row * N + colb[ni]]  = v;
            }
        }
    }
}

// ---------------------------------------------------------------------------
// Fused: softmax (spec cancels: constant along softmax axis) + locations +
// bilinear sampling + aggregation. One block per (b,q), 256 threads.
// axyhid layout: row stride 512 = [ax(128) | ay(128) | hid(256)]
// ---------------------------------------------------------------------------
__device__ __forceinline__
float corner_val_bf(const __bf16* __restrict__ vb, int st, int Hl, int Wl,
                    int xi, int yi, float w, int hd)
{
    const bool valid = (xi >= 0) & (xi < Wl) & (yi >= 0) & (yi < Hl);
    const int idx = min(max(yi, 0), Hl - 1) * Wl + min(max(xi, 0), Wl - 1);
    const float g = (float)vb[(size_t)(st + idx) * 256 + hd];
    return valid ? g * w : 0.f;
}

__global__ __launch_bounds__(256)
void attn_sample_kernel(const float* __restrict__ axyhid,
                        const float* __restrict__ refp, const float* __restrict__ objs,
                        const float* __restrict__ off, const __bf16* __restrict__ v,
                        float* __restrict__ agg)
{
    const int bq = blockIdx.x;
    const int b  = bq / Q_;
    const int tid = threadIdx.x;

    __shared__ float sm[128];
    __shared__ float sa[128];
    __shared__ float sl[256];

    if (tid < 128)
        sm[tid] = axyhid[(size_t)bq * 512 + tid] * axyhid[(size_t)bq * 512 + 128 + tid];
    __syncthreads();

    if (tid < 128) {
        const int h = tid >> 4;
        float mx = -1e30f;
        #pragma unroll
        for (int i = 0; i < 16; ++i) mx = fmaxf(mx, sm[h * 16 + i]);
        float s = 0.f;
        #pragma unroll
        for (int i = 0; i < 16; ++i) s += __expf(sm[h * 16 + i] - mx);
        sa[tid] = __expf(sm[tid] - mx) / s;

        const int l = (tid >> 2) & 3;
        const float os0 = objs[(size_t)bq * 2], os1 = objs[(size_t)bq * 2 + 1];
        const float r0 = refp[((size_t)bq * 4 + l) * 2];
        const float r1 = refp[((size_t)bq * 4 + l) * 2 + 1];
        const float o0 = off[(size_t)bq * 256 + tid * 2]     * os0;
        const float o1 = off[(size_t)bq * 256 + tid * 2 + 1] * os1;
        sl[tid * 2]     = fminf(fmaxf(r0 + o0, 0.f), 1.f);
        sl[tid * 2 + 1] = fminf(fmaxf(r1 + o1, 0.f), 1.f);
    }
    __syncthreads();

    const int h = tid >> 5, d = tid & 31;
    const int hd = h * 32 + d;
    const __bf16* vb = v + (size_t)b * S_ * 256;

    const int Hl_arr[4] = {100, 50, 25, 13};
    const int Wl_arr[4] = {100, 50, 25, 13};
    const int st_arr[4] = {0, 10000, 12500, 13125};

    float acc = 0.f;
    #pragma unroll
    for (int lvl = 0; lvl < 4; ++lvl) {
        const int Hl = Hl_arr[lvl], Wl = Wl_arr[lvl], st = st_arr[lvl];
        #pragma unroll
        for (int p = 0; p < 4; ++p) {
            const int li = (h * 4 + lvl) * 4 + p;
            const float lx = sl[li * 2], ly = sl[li * 2 + 1];
            const float a  = sa[li];
            const float x = lx * (float)Wl - 0.5f;
            const float y = ly * (float)Hl - 0.5f;
            const float x0f = floorf(x), y0f = floorf(y);
            const float fx = x - x0f, fy = y - y0f;
            const int x0 = (int)x0f, y0 = (int)y0f;
            const float w00 = (1.f - fx) * (1.f - fy);
            const float w10 = fx * (1.f - fy);
            const float w01 = (1.f - fx) * fy;
            const float w11 = fx * fy;
            float s = 0.f;
            s += corner_val_bf(vb, st, Hl, Wl, x0,     y0,     w00, hd);
            s += corner_val_bf(vb, st, Hl, Wl, x0 + 1, y0,     w10, hd);
            s += corner_val_bf(vb, st, Hl, Wl, x0,     y0 + 1, w01, hd);
            s += corner_val_bf(vb, st, Hl, Wl, x0 + 1, y0 + 1, w11, hd);
            acc += a * s;
        }
    }
    agg[(size_t)bq * 256 + tid] = acc;
}

// ---------------------------------------------------------------------------
extern "C" void kernel_launch(void* const* d_in, const int* in_sizes, int n_in,
                              void* d_out, int out_size, void* d_ws, size_t ws_size,
                              hipStream_t stream)
{
    const float* query = (const float*)d_in[0];
    const float* refp  = (const float*)d_in[1];
    const float* x_in  = (const float*)d_in[2];
    const float* objs  = (const float*)d_in[3];
    const float* w_q    = (const float*)d_in[6];
    const float* b_q    = (const float*)d_in[7];
    const float* w_v    = (const float*)d_in[8];
    const float* b_v    = (const float*)d_in[9];
    const float* w_o    = (const float*)d_in[10];
    const float* b_o    = (const float*)d_in[11];
    const float* w_off1 = (const float*)d_in[12];
    const float* b_off1 = (const float*)d_in[13];
    const float* w_off2 = (const float*)d_in[14];
    const float* b_off2 = (const float*)d_in[15];
    const float* w_ax   = (const float*)d_in[16];
    const float* b_ax   = (const float*)d_in[17];
    const float* w_ay   = (const float*)d_in[18];
    const float* b_ay   = (const float*)d_in[19];

    float* ws = (float*)d_ws;
    float* axyhid_ws = ws;                               // BQ*512 f32
    float* off_ws    = axyhid_ws + (size_t)BQ * 512;     // BQ*256 f32
    float* agg_ws    = off_ws    + (size_t)BQ * 256;     // BQ*256 f32
    float* bcomb_ws  = agg_ws    + (size_t)BQ * 256;     // 512 f32
    __bf16* v_bf    = (__bf16*)(bcomb_ws + 512);         // BS*256 bf16
    __bf16* wt_v    = v_bf    + (size_t)BS * 256;
    __bf16* wt_o    = wt_v    + 256 * 256;
    __bf16* wt_off2 = wt_o    + 256 * 256;
    __bf16* wt_cat  = wt_off2 + 256 * 256;               // 512*256
    __bf16* wcomb   = wt_cat  + 512 * 256;               // 512*256

    const dim3 blk(256);

    // weight prep
    transpose_all<<<320, blk, 0, stream>>>(w_v, w_o, w_off1, w_off2, w_ax, w_ay,
                                           wt_v, wt_o, wt_off2, wt_cat);
    combine_w<<<8, blk, 0, stream>>>(wt_cat, w_q, wcomb);
    combine_bias<<<2, blk, 0, stream>>>(wt_cat, b_q, b_ax, b_ay, b_off1, bcomb_ws);

    // v = x_in @ w_v + b_v -> bf16
    gemm_bf16<false, true><<<dim3(2, (BS + 127) / 128), blk, 0, stream>>>(
        x_in, wt_v, b_v, nullptr, nullptr, v_bf, BS, 256, 256);

    // [ax|ay|hid] = query @ Wcomb + bcomb (+obj rank-2 & relu on hid cols)
    gemm_bf16<true, false><<<dim3(4, (BQ + 127) / 128), blk, 0, stream>>>(
        query, wcomb, bcomb_ws, objs, w_off1 + 256 * 256, axyhid_ws, BQ, 512, 256);

    // offsets = hid @ w_off2 + b_off2 -> f32
    gemm_bf16<false, false><<<dim3(2, (BQ + 127) / 128), blk, 0, stream>>>(
        axyhid_ws + 256, wt_off2, b_off2, nullptr, nullptr, off_ws, BQ, 256, 512);

    // fused softmax/locs/sampling
    attn_sample_kernel<<<BQ, blk, 0, stream>>>(axyhid_ws, refp, objs, off_ws,
                                               v_bf, agg_ws);

    // out = agg @ w_o + b_o -> f32
    gemm_bf16<false, false><<<dim3(2, (BQ + 127) / 128), blk, 0, stream>>>(
        agg_ws, wt_o, b_o, nullptr, nullptr, (float*)d_out, BQ, 256, 256);
}

// Round 8
// 152.734 us; speedup vs baseline: 1.4356x; 1.0609x over previous
//
#include <hip/hip_runtime.h>
#include <hip/hip_bf16.h>
#include <math.h>

// Problem constants (from reference)
constexpr int B_ = 8, Q_ = 900;
constexpr int S_ = 13294;
constexpr int BQ = 7200;     // B*Q
constexpr int BS = 106352;   // B*S

typedef __bf16 bf16x8 __attribute__((ext_vector_type(8)));
typedef float  f32x4  __attribute__((ext_vector_type(4)));

#define WAITLGKM0 asm volatile("s_waitcnt lgkmcnt(0)" ::: "memory")
#define SCHEDB    __builtin_amdgcn_sched_barrier(0)
#define BAR       __builtin_amdgcn_s_barrier()
#define CFENCE    asm volatile("" ::: "memory")

__device__ __forceinline__ void load_lds16(const void* g, void* lds) {
    __builtin_amdgcn_global_load_lds(
        (const __attribute__((address_space(1))) void*)g,
        (__attribute__((address_space(3))) void*)lds, 16, 0, 0);
}

// ---------------------------------------------------------------------------
// Fused transpose+cast of weights into bf16 [N][K=256] layouts.
// bi 0..63: w_v -> tv | 64..127: w_o -> to | 128..191: w_off2 -> toff2
// 192..319: [w_ax | w_ay | w_off1(:256)] -> tcat[512][256]
// ---------------------------------------------------------------------------
__global__ __launch_bounds__(256)
void transpose_all(const float* __restrict__ wv, const float* __restrict__ wo,
                   const float* __restrict__ woff1, const float* __restrict__ woff2,
                   const float* __restrict__ wax, const float* __restrict__ way,
                   __bf16* __restrict__ tv, __bf16* __restrict__ to_,
                   __bf16* __restrict__ toff2, __bf16* __restrict__ tcat)
{
    const int bi = blockIdx.x;
    __shared__ float tile[32][33];
    const int tx = threadIdx.x & 31, ty = threadIdx.x >> 5;

    const float* src; __bf16* dst; int k0, n0, scol, sN = 256;
    if (bi < 192) {
        const int wid = bi >> 6, t = bi & 63;
        k0 = (t & 7) * 32; n0 = (t >> 3) * 32; scol = n0;
        if      (wid == 0) { src = wv;    dst = tv;    }
        else if (wid == 1) { src = wo;    dst = to_;   }
        else               { src = woff2; dst = toff2; }
    } else {
        const int t = bi - 192;                  // 0..127
        k0 = (t & 7) * 32; n0 = (t >> 3) * 32;   // n0 0..480
        dst = tcat;
        if      (n0 < 128) { src = wax;   scol = n0;       sN = 128; }
        else if (n0 < 256) { src = way;   scol = n0 - 128; sN = 128; }
        else               { src = woff1; scol = n0 - 256; sN = 256; }
    }

    #pragma unroll
    for (int i = 0; i < 4; ++i)
        tile[ty + 8 * i][tx] = src[(size_t)(k0 + ty + 8 * i) * sN + scol + tx];
    __syncthreads();
    #pragma unroll
    for (int i = 0; i < 4; ++i)
        dst[(size_t)(n0 + ty + 8 * i) * 256 + k0 + tx] = (__bf16)tile[tx][ty + 8 * i];
}

// ---------------------------------------------------------------------------
// Wcomb[n][k] = sum_c tcat[n][c] * wq[k][c]   (512x256x256, bf16 out)
// ---------------------------------------------------------------------------
__global__ __launch_bounds__(256)
void combine_w(const __bf16* __restrict__ tcat, const float* __restrict__ wq,
               __bf16* __restrict__ wcomb)
{
    const int wid  = (blockIdx.x << 2) + (threadIdx.x >> 6);
    const int lane = threadIdx.x & 63;
    const int n0 = (wid >> 2) * 64, k0 = (wid & 3) * 64;
    const int l15 = lane & 15, l4 = lane >> 4;

    f32x4 acc[4][4] = {};
    #pragma unroll
    for (int s = 0; s < 8; ++s) {
        const int c0 = s * 32 + l4 * 8;
        bf16x8 am[4], bm[4];
        #pragma unroll
        for (int mi = 0; mi < 4; ++mi)
            am[mi] = *(const bf16x8*)(tcat + (size_t)(n0 + mi * 16 + l15) * 256 + c0);
        #pragma unroll
        for (int ni = 0; ni < 4; ++ni) {
            const float* wr_ = wq + (size_t)(k0 + ni * 16 + l15) * 256 + c0;
            const float4 f0 = ((const float4*)wr_)[0];
            const float4 f1 = ((const float4*)wr_)[1];
            bm[ni][0] = (__bf16)f0.x; bm[ni][1] = (__bf16)f0.y;
            bm[ni][2] = (__bf16)f0.z; bm[ni][3] = (__bf16)f0.w;
            bm[ni][4] = (__bf16)f1.x; bm[ni][5] = (__bf16)f1.y;
            bm[ni][6] = (__bf16)f1.z; bm[ni][7] = (__bf16)f1.w;
        }
        #pragma unroll
        for (int mi = 0; mi < 4; ++mi)
            #pragma unroll
            for (int ni = 0; ni < 4; ++ni)
                acc[mi][ni] = __builtin_amdgcn_mfma_f32_16x16x32_bf16(
                    am[mi], bm[ni], acc[mi][ni], 0, 0, 0);
    }
    #pragma unroll
    for (int mi = 0; mi < 4; ++mi)
        #pragma unroll
        for (int rr = 0; rr < 4; ++rr) {
            const int n = n0 + mi * 16 + l4 * 4 + rr;
            #pragma unroll
            for (int ni = 0; ni < 4; ++ni)
                wcomb[(size_t)n * 256 + k0 + ni * 16 + l15] = (__bf16)acc[mi][ni][rr];
        }
}

// bcomb[n] = sum_c b_q[c]*tcat[n][c] + (n<128? b_ax[n] : n<256? b_ay[n-128] : b_off1[n-256])
__global__ __launch_bounds__(256)
void combine_bias(const __bf16* __restrict__ tcat, const float* __restrict__ bq,
                  const float* __restrict__ bax, const float* __restrict__ bay,
                  const float* __restrict__ boff1, float* __restrict__ bcomb)
{
    const int n = blockIdx.x * 256 + threadIdx.x;
    float acc = (n < 128) ? bax[n] : (n < 256 ? bay[n - 128] : boff1[n - 256]);
    const __bf16* row = tcat + (size_t)n * 256;
    #pragma unroll 4
    for (int c8 = 0; c8 < 32; ++c8) {
        const bf16x8 rv = *(const bf16x8*)(row + c8 * 8);
        #pragma unroll
        for (int j = 0; j < 8; ++j) acc += bq[c8 * 8 + j] * (float)rv[j];
    }
    bcomb[n] = acc;
}

// ---------------------------------------------------------------------------
// Deep-pipelined bf16 MFMA GEMM (R7-verified mappings, new sync skeleton).
// C[M,N] = A[M,K=256](f32,LDA) @ Wt[N,256](bf16) + bias -> f32/bf16
// BM=BN=128, BK=32, 8 K-steps fully unrolled, 4 waves (2x2), 64x64/wave.
// A: reg-staged 2-deep (2 reg sets; A(u+2) issued at iter u, ds_write at end
//    of iter u+1, swizzled — VERIFIED R3/R7 mapping).
// B: global_load_lds, 3 LDS buffers, B(u+2) issued at iter u (VERIFIED swizzle).
// Sync: lgkmcnt(0)+s_barrier only. No vmcnt(0) drain: the compiler's own
// register-dep wait before writeA (vmcnt(6): 6 younger ops) implicitly drains
// the older B(u) glds right before the barrier preceding iter u+1 [FIFO vmcnt].
// RELUHI: cols>=256 get rank-2 obj update (w_off1 extra rows) + relu.
// ---------------------------------------------------------------------------
template<bool RELUHI, bool OUTBF16>
__global__ __launch_bounds__(256)
void gemm_dp(const float* __restrict__ A, const __bf16* __restrict__ Wt,
             const float* __restrict__ bias, const float* __restrict__ extra,
             const float* __restrict__ Wex, void* __restrict__ outp,
             int M, int N, int LDA)
{
    __shared__ float4 AsbV[2][512];   // 2 x 8KB  (A bufs, bf16 128x32)
    __shared__ float4 BsbV[3][512];   // 3 x 8KB  (B bufs, bf16 128x32)
    char* const Asb_b = (char*)AsbV;
    char* const Bsb_b = (char*)BsbV;

    const int tid  = threadIdx.x;
    const int wave = tid >> 6, lane = tid & 63;
    const int wr = wave >> 1, wc = wave & 1;
    const int row0 = blockIdx.y * 128, col0 = blockIdx.x * 128;
    const int l15 = lane & 15, l4 = lane >> 4;

    // A staging: thread t -> row=t>>1, k-half=t&1 (16 f32 each)  [VERIFIED]
    const int st_row = tid >> 1, st_kh = tid & 1;
    const int gr_cl  = min(row0 + st_row, M - 1);
    const float* Abase = A + (size_t)gr_cl * LDA + st_kh * 16;
    const int asw   = (st_row >> 1) & 3;
    const int a_wo0 = st_row * 64 + ((st_kh * 2)     ^ asw) * 16;
    const int a_wo1 = st_row * 64 + ((st_kh * 2 + 1) ^ asw) * 16;

    // fragment read offsets  [VERIFIED]
    int a_off[4], b_off[4];
    #pragma unroll
    for (int mi = 0; mi < 4; ++mi) {
        const int r   = wr * 64 + mi * 16 + l15;
        const int kcp = l4 ^ ((r >> 1) & 3);
        a_off[mi] = r * 64 + kcp * 16;
    }
    #pragma unroll
    for (int ni = 0; ni < 4; ++ni) {
        const int c   = wc * 64 + ni * 16 + l15;
        const int kcp = l4 ^ ((c >> 1) & 3);
        b_off[ni] = c * 64 + kcp * 16;
    }

    // B staging source (source-side swizzle)  [VERIFIED]
    const __bf16* bsrc[2];
    #pragma unroll
    for (int i = 0; i < 2; ++i) {
        const int c   = (wave * 2 + i) * 64 + lane;
        const int col = c >> 2, kcp = c & 3;
        const int kc  = kcp ^ ((col >> 1) & 3);
        bsrc[i] = Wt + (size_t)(col0 + col) * 256 + kc * 8;
    }

    auto issueB = [&](int kt, int bbuf) {
        #pragma unroll
        for (int i = 0; i < 2; ++i)
            load_lds16(bsrc[i] + kt * 32, Bsb_b + bbuf * 8192 + (wave * 2 + i) * 1024);
    };
    auto loadA = [&](int kt, float4* g) {
        const float* ga = Abase + kt * 32;
        g[0] = ((const float4*)ga)[0];
        g[1] = ((const float4*)ga)[1];
        g[2] = ((const float4*)ga)[2];
        g[3] = ((const float4*)ga)[3];
    };
    auto writeA = [&](int abuf, const float4* g) {
        bf16x8 c0, c1;
        c0[0] = (__bf16)g[0].x; c0[1] = (__bf16)g[0].y; c0[2] = (__bf16)g[0].z; c0[3] = (__bf16)g[0].w;
        c0[4] = (__bf16)g[1].x; c0[5] = (__bf16)g[1].y; c0[6] = (__bf16)g[1].z; c0[7] = (__bf16)g[1].w;
        c1[0] = (__bf16)g[2].x; c1[1] = (__bf16)g[2].y; c1[2] = (__bf16)g[2].z; c1[3] = (__bf16)g[2].w;
        c1[4] = (__bf16)g[3].x; c1[5] = (__bf16)g[3].y; c1[6] = (__bf16)g[3].z; c1[7] = (__bf16)g[3].w;
        *(bf16x8*)(Asb_b + abuf * 8192 + a_wo0) = c0;
        *(bf16x8*)(Asb_b + abuf * 8192 + a_wo1) = c1;
    };

    f32x4 acc[4][4] = {};
    float4 g[2][4];   // two A-prefetch register sets (static indices via unroll)

    // prologue: B(0), A(0)-regs, B(1), A(1)-regs; A(0) -> LDS
    issueB(0, 0);
    loadA(0, g[0]);
    issueB(1, 1);
    loadA(1, g[1]);
    writeA(0, g[0]);      // compiler waits g[0] (vmcnt(6)) -> drains B(0) too
    WAITLGKM0; BAR; CFENCE; SCHEDB;

    #pragma unroll
    for (int u = 0; u < 8; ++u) {
        // issue 2-ahead (A into reg set u&1 — its prior contents were
        // consumed by writeA at end of iter u-1)
        if (u + 2 <= 7) {
            loadA(u + 2, g[u & 1]);
            issueB(u + 2, (u + 2) % 3);
        }

        // read fragments of tile u (compiler inserts precise lgkmcnt waits)
        const char* Ab = Asb_b + (u & 1) * 8192;
        const char* Bb = Bsb_b + (u % 3) * 8192;
        bf16x8 a[4], b[4];
        #pragma unroll
        for (int mi = 0; mi < 4; ++mi) a[mi] = *(const bf16x8*)(Ab + a_off[mi]);
        #pragma unroll
        for (int ni = 0; ni < 4; ++ni) b[ni] = *(const bf16x8*)(Bb + b_off[ni]);

        #pragma unroll
        for (int mi = 0; mi < 4; ++mi)
            #pragma unroll
            for (int ni = 0; ni < 4; ++ni)
                acc[mi][ni] = __builtin_amdgcn_mfma_f32_16x16x32_bf16(
                    a[mi], b[ni], acc[mi][ni], 0, 0, 0);

        if (u + 1 <= 7) {
            // write A(u+1) into the other A buffer; compiler's reg-dep wait
            // here is vmcnt(6) (A(u+2)4 + B(u+2)2 younger) -> drains B(u+1)? no:
            // drains everything OLDER than A(u+1), i.e. B(u+1)'s glds were
            // issued AFTER A(u+1) in iter u-1? Order per iter: loadA then
            // issueB -> B(u+1) is younger than A(u+1) by 2 -> wait leaves it.
            // B(u+1) is drained by NEXT iter's writeA wait (vmcnt(6)), before
            // the barrier that precedes reading it in iter u+1.  [FIFO vmcnt]
            writeA((u + 1) & 1, g[(u + 1) & 1]);
            WAITLGKM0; BAR; CFENCE; SCHEDB;
        }
    }

    // epilogue
    int   colb[4];
    float bb[4], we0[4], we1[4];
    #pragma unroll
    for (int ni = 0; ni < 4; ++ni) {
        const int c = col0 + wc * 64 + ni * 16 + l15;
        colb[ni] = c;
        bb[ni]   = bias[c];
        if (RELUHI && c >= 256) { we0[ni] = Wex[c - 256]; we1[ni] = Wex[c - 256 + 256]; }
        else                    { we0[ni] = 0.f; we1[ni] = 0.f; }
    }
    #pragma unroll
    for (int mi = 0; mi < 4; ++mi) {
        #pragma unroll
        for (int rr = 0; rr < 4; ++rr) {
            const int row = row0 + wr * 64 + mi * 16 + l4 * 4 + rr;
            if (row >= M) continue;
            float e0 = 0.f, e1 = 0.f;
            if (RELUHI) { e0 = extra[(size_t)row * 2]; e1 = extra[(size_t)row * 2 + 1]; }
            #pragma unroll
            for (int ni = 0; ni < 4; ++ni) {
                float v = acc[mi][ni][rr] + bb[ni];
                if (RELUHI && colb[ni] >= 256) {
                    v += e0 * we0[ni] + e1 * we1[ni];
                    v = fmaxf(v, 0.f);
                }
                if (OUTBF16) ((__bf16*)outp)[(size_t)row * N + colb[ni]] = (__bf16)v;
                else         ((float*)outp)[(size_t)row * N + colb[ni]]  = v;
            }
        }
    }
}

// ---------------------------------------------------------------------------
// Fused: softmax (spec cancels) + locations + bilinear sampling + aggregation.
// One block per (b,q), 256 threads. axyhid stride 512 = [ax|ay|hid]
// ---------------------------------------------------------------------------
__device__ __forceinline__
float corner_val_bf(const __bf16* __restrict__ vb, int st, int Hl, int Wl,
                    int xi, int yi, float w, int hd)
{
    const bool valid = (xi >= 0) & (xi < Wl) & (yi >= 0) & (yi < Hl);
    const int idx = min(max(yi, 0), Hl - 1) * Wl + min(max(xi, 0), Wl - 1);
    const float g = (float)vb[(size_t)(st + idx) * 256 + hd];
    return valid ? g * w : 0.f;
}

__global__ __launch_bounds__(256)
void attn_sample_kernel(const float* __restrict__ axyhid,
                        const float* __restrict__ refp, const float* __restrict__ objs,
                        const float* __restrict__ off, const __bf16* __restrict__ v,
                        float* __restrict__ agg)
{
    const int bq = blockIdx.x;
    const int b  = bq / Q_;
    const int tid = threadIdx.x;

    __shared__ float sm[128];
    __shared__ float sa[128];
    __shared__ float sl[256];

    if (tid < 128)
        sm[tid] = axyhid[(size_t)bq * 512 + tid] * axyhid[(size_t)bq * 512 + 128 + tid];
    __syncthreads();

    if (tid < 128) {
        const int h = tid >> 4;
        float mx = -1e30f;
        #pragma unroll
        for (int i = 0; i < 16; ++i) mx = fmaxf(mx, sm[h * 16 + i]);
        float s = 0.f;
        #pragma unroll
        for (int i = 0; i < 16; ++i) s += __expf(sm[h * 16 + i] - mx);
        sa[tid] = __expf(sm[tid] - mx) / s;

        const int l = (tid >> 2) & 3;
        const float os0 = objs[(size_t)bq * 2], os1 = objs[(size_t)bq * 2 + 1];
        const float r0 = refp[((size_t)bq * 4 + l) * 2];
        const float r1 = refp[((size_t)bq * 4 + l) * 2 + 1];
        const float o0 = off[(size_t)bq * 256 + tid * 2]     * os0;
        const float o1 = off[(size_t)bq * 256 + tid * 2 + 1] * os1;
        sl[tid * 2]     = fminf(fmaxf(r0 + o0, 0.f), 1.f);
        sl[tid * 2 + 1] = fminf(fmaxf(r1 + o1, 0.f), 1.f);
    }
    __syncthreads();

    const int h = tid >> 5, d = tid & 31;
    const int hd = h * 32 + d;
    const __bf16* vb = v + (size_t)b * S_ * 256;

    const int Hl_arr[4] = {100, 50, 25, 13};
    const int Wl_arr[4] = {100, 50, 25, 13};
    const int st_arr[4] = {0, 10000, 12500, 13125};

    float acc = 0.f;
    #pragma unroll
    for (int lvl = 0; lvl < 4; ++lvl) {
        const int Hl = Hl_arr[lvl], Wl = Wl_arr[lvl], st = st_arr[lvl];
        #pragma unroll
        for (int p = 0; p < 4; ++p) {
            const int li = (h * 4 + lvl) * 4 + p;
            const float lx = sl[li * 2], ly = sl[li * 2 + 1];
            const float a  = sa[li];
            const float x = lx * (float)Wl - 0.5f;
            const float y = ly * (float)Hl - 0.5f;
            const float x0f = floorf(x), y0f = floorf(y);
            const float fx = x - x0f, fy = y - y0f;
            const int x0 = (int)x0f, y0 = (int)y0f;
            const float w00 = (1.f - fx) * (1.f - fy);
            const float w10 = fx * (1.f - fy);
            const float w01 = (1.f - fx) * fy;
            const float w11 = fx * fy;
            float s = 0.f;
            s += corner_val_bf(vb, st, Hl, Wl, x0,     y0,     w00, hd);
            s += corner_val_bf(vb, st, Hl, Wl, x0 + 1, y0,     w10, hd);
            s += corner_val_bf(vb, st, Hl, Wl, x0,     y0 + 1, w01, hd);
            s += corner_val_bf(vb, st, Hl, Wl, x0 + 1, y0 + 1, w11, hd);
            acc += a * s;
        }
    }
    agg[(size_t)bq * 256 + tid] = acc;
}

// ---------------------------------------------------------------------------
extern "C" void kernel_launch(void* const* d_in, const int* in_sizes, int n_in,
                              void* d_out, int out_size, void* d_ws, size_t ws_size,
                              hipStream_t stream)
{
    const float* query = (const float*)d_in[0];
    const float* refp  = (const float*)d_in[1];
    const float* x_in  = (const float*)d_in[2];
    const float* objs  = (const float*)d_in[3];
    const float* w_q    = (const float*)d_in[6];
    const float* b_q    = (const float*)d_in[7];
    const float* w_v    = (const float*)d_in[8];
    const float* b_v    = (const float*)d_in[9];
    const float* w_o    = (const float*)d_in[10];
    const float* b_o    = (const float*)d_in[11];
    const float* w_off1 = (const float*)d_in[12];
    const float* b_off1 = (const float*)d_in[13];
    const float* w_off2 = (const float*)d_in[14];
    const float* b_off2 = (const float*)d_in[15];
    const float* w_ax   = (const float*)d_in[16];
    const float* b_ax   = (const float*)d_in[17];
    const float* w_ay   = (const float*)d_in[18];
    const float* b_ay   = (const float*)d_in[19];

    float* ws = (float*)d_ws;
    float* axyhid_ws = ws;                               // BQ*512 f32
    float* off_ws    = axyhid_ws + (size_t)BQ * 512;     // BQ*256 f32
    float* agg_ws    = off_ws    + (size_t)BQ * 256;     // BQ*256 f32
    float* bcomb_ws  = agg_ws    + (size_t)BQ * 256;     // 512 f32
    __bf16* v_bf    = (__bf16*)(bcomb_ws + 512);         // BS*256 bf16
    __bf16* wt_v    = v_bf    + (size_t)BS * 256;
    __bf16* wt_o    = wt_v    + 256 * 256;
    __bf16* wt_off2 = wt_o    + 256 * 256;
    __bf16* wt_cat  = wt_off2 + 256 * 256;               // 512*256
    __bf16* wcomb   = wt_cat  + 512 * 256;               // 512*256

    const dim3 blk(256);

    // weight prep
    transpose_all<<<320, blk, 0, stream>>>(w_v, w_o, w_off1, w_off2, w_ax, w_ay,
                                           wt_v, wt_o, wt_off2, wt_cat);
    combine_w<<<8, blk, 0, stream>>>(wt_cat, w_q, wcomb);
    combine_bias<<<2, blk, 0, stream>>>(wt_cat, b_q, b_ax, b_ay, b_off1, bcomb_ws);

    // v = x_in @ w_v + b_v -> bf16
    gemm_dp<false, true><<<dim3(2, (BS + 127) / 128), blk, 0, stream>>>(
        x_in, wt_v, b_v, nullptr, nullptr, v_bf, BS, 256, 256);

    // [ax|ay|hid] = query @ Wcomb + bcomb (+obj rank-2 & relu on hid cols)
    gemm_dp<true, false><<<dim3(4, (BQ + 127) / 128), blk, 0, stream>>>(
        query, wcomb, bcomb_ws, objs, w_off1 + 256 * 256, axyhid_ws, BQ, 512, 256);

    // offsets = hid @ w_off2 + b_off2 -> f32
    gemm_dp<false, false><<<dim3(2, (BQ + 127) / 128), blk, 0, stream>>>(
        axyhid_ws + 256, wt_off2, b_off2, nullptr, nullptr, off_ws, BQ, 256, 512);

    // fused softmax/locs/sampling
    attn_sample_kernel<<<BQ, blk, 0, stream>>>(axyhid_ws, refp, objs, off_ws,
                                               v_bf, agg_ws);

    // out = agg @ w_o + b_o -> f32
    gemm_dp<false, false><<<dim3(2, (BQ + 127) / 128), blk, 0, stream>>>(
        agg_ws, wt_o, b_o, nullptr, nullptr, (float*)d_out, BQ, 256, 256);
}

// Round 9
// 126.921 us; speedup vs baseline: 1.7275x; 1.2034x over previous
//
#include <hip/hip_runtime.h>
#include <hip/hip_bf16.h>
#include <math.h>

// Problem constants (from reference)
constexpr int B_ = 8, Q_ = 900;
constexpr int S_ = 13294;
constexpr int BQ = 7200;     // B*Q
constexpr int BS = 106352;   // B*S

typedef __bf16 bf16x8 __attribute__((ext_vector_type(8)));
typedef float  f32x4  __attribute__((ext_vector_type(4)));

#define WAITLGKM0 asm volatile("s_waitcnt lgkmcnt(0)" ::: "memory")
#define SCHEDB    __builtin_amdgcn_sched_barrier(0)
#define BAR       __builtin_amdgcn_s_barrier()
#define CFENCE    asm volatile("" ::: "memory")

__device__ __forceinline__ void load_lds16(const void* g, void* lds) {
    __builtin_amdgcn_global_load_lds(
        (const __attribute__((address_space(1))) void*)g,
        (__attribute__((address_space(3))) void*)lds, 16, 0, 0);
}

// ---------------------------------------------------------------------------
// Fused transpose+cast of weights into bf16 [N][K=256] layouts.
// bi 0..63: w_v -> tv | 64..127: w_o -> to | 128..191: w_off2 -> toff2
// 192..319: [w_ax | w_ay | w_off1(:256)] -> tcat[512][256]
// ---------------------------------------------------------------------------
__global__ __launch_bounds__(256)
void transpose_all(const float* __restrict__ wv, const float* __restrict__ wo,
                   const float* __restrict__ woff1, const float* __restrict__ woff2,
                   const float* __restrict__ wax, const float* __restrict__ way,
                   __bf16* __restrict__ tv, __bf16* __restrict__ to_,
                   __bf16* __restrict__ toff2, __bf16* __restrict__ tcat)
{
    const int bi = blockIdx.x;
    __shared__ float tile[32][33];
    const int tx = threadIdx.x & 31, ty = threadIdx.x >> 5;

    const float* src; __bf16* dst; int k0, n0, scol, sN = 256;
    if (bi < 192) {
        const int wid = bi >> 6, t = bi & 63;
        k0 = (t & 7) * 32; n0 = (t >> 3) * 32; scol = n0;
        if      (wid == 0) { src = wv;    dst = tv;    }
        else if (wid == 1) { src = wo;    dst = to_;   }
        else               { src = woff2; dst = toff2; }
    } else {
        const int t = bi - 192;                  // 0..127
        k0 = (t & 7) * 32; n0 = (t >> 3) * 32;   // n0 0..480
        dst = tcat;
        if      (n0 < 128) { src = wax;   scol = n0;       sN = 128; }
        else if (n0 < 256) { src = way;   scol = n0 - 128; sN = 128; }
        else               { src = woff1; scol = n0 - 256; sN = 256; }
    }

    #pragma unroll
    for (int i = 0; i < 4; ++i)
        tile[ty + 8 * i][tx] = src[(size_t)(k0 + ty + 8 * i) * sN + scol + tx];
    __syncthreads();
    #pragma unroll
    for (int i = 0; i < 4; ++i)
        dst[(size_t)(n0 + ty + 8 * i) * 256 + k0 + tx] = (__bf16)tile[tx][ty + 8 * i];
}

// ---------------------------------------------------------------------------
// Wcomb[n][k] = sum_c tcat[n][c] * wq[k][c]   (512x256x256, bf16 out)
// ---------------------------------------------------------------------------
__global__ __launch_bounds__(256)
void combine_w(const __bf16* __restrict__ tcat, const float* __restrict__ wq,
               __bf16* __restrict__ wcomb)
{
    const int wid  = (blockIdx.x << 2) + (threadIdx.x >> 6);
    const int lane = threadIdx.x & 63;
    const int n0 = (wid >> 2) * 64, k0 = (wid & 3) * 64;
    const int l15 = lane & 15, l4 = lane >> 4;

    f32x4 acc[4][4] = {};
    #pragma unroll
    for (int s = 0; s < 8; ++s) {
        const int c0 = s * 32 + l4 * 8;
        bf16x8 am[4], bm[4];
        #pragma unroll
        for (int mi = 0; mi < 4; ++mi)
            am[mi] = *(const bf16x8*)(tcat + (size_t)(n0 + mi * 16 + l15) * 256 + c0);
        #pragma unroll
        for (int ni = 0; ni < 4; ++ni) {
            const float* wr_ = wq + (size_t)(k0 + ni * 16 + l15) * 256 + c0;
            const float4 f0 = ((const float4*)wr_)[0];
            const float4 f1 = ((const float4*)wr_)[1];
            bm[ni][0] = (__bf16)f0.x; bm[ni][1] = (__bf16)f0.y;
            bm[ni][2] = (__bf16)f0.z; bm[ni][3] = (__bf16)f0.w;
            bm[ni][4] = (__bf16)f1.x; bm[ni][5] = (__bf16)f1.y;
            bm[ni][6] = (__bf16)f1.z; bm[ni][7] = (__bf16)f1.w;
        }
        #pragma unroll
        for (int mi = 0; mi < 4; ++mi)
            #pragma unroll
            for (int ni = 0; ni < 4; ++ni)
                acc[mi][ni] = __builtin_amdgcn_mfma_f32_16x16x32_bf16(
                    am[mi], bm[ni], acc[mi][ni], 0, 0, 0);
    }
    #pragma unroll
    for (int mi = 0; mi < 4; ++mi)
        #pragma unroll
        for (int rr = 0; rr < 4; ++rr) {
            const int n = n0 + mi * 16 + l4 * 4 + rr;
            #pragma unroll
            for (int ni = 0; ni < 4; ++ni)
                wcomb[(size_t)n * 256 + k0 + ni * 16 + l15] = (__bf16)acc[mi][ni][rr];
        }
}

// bcomb[n] = sum_c b_q[c]*tcat[n][c] + (n<128? b_ax[n] : n<256? b_ay[n-128] : b_off1[n-256])
__global__ __launch_bounds__(256)
void combine_bias(const __bf16* __restrict__ tcat, const float* __restrict__ bq,
                  const float* __restrict__ bax, const float* __restrict__ bay,
                  const float* __restrict__ boff1, float* __restrict__ bcomb)
{
    const int n = blockIdx.x * 256 + threadIdx.x;
    float acc = (n < 128) ? bax[n] : (n < 256 ? bay[n - 128] : boff1[n - 256]);
    const __bf16* row = tcat + (size_t)n * 256;
    #pragma unroll 4
    for (int c8 = 0; c8 < 32; ++c8) {
        const bf16x8 rv = *(const bf16x8*)(row + c8 * 8);
        #pragma unroll
        for (int j = 0; j < 8; ++j) acc += bq[c8 * 8 + j] * (float)rv[j];
    }
    bcomb[n] = acc;
}

// ---------------------------------------------------------------------------
// Deep-pipelined bf16 MFMA GEMM (verified R8).
// C[M,N] = A[M,K=256](f32,LDA) @ Wt[N,256](bf16) + bias -> f32/bf16
// ---------------------------------------------------------------------------
template<bool RELUHI, bool OUTBF16>
__global__ __launch_bounds__(256)
void gemm_dp(const float* __restrict__ A, const __bf16* __restrict__ Wt,
             const float* __restrict__ bias, const float* __restrict__ extra,
             const float* __restrict__ Wex, void* __restrict__ outp,
             int M, int N, int LDA)
{
    __shared__ float4 AsbV[2][512];   // 2 x 8KB  (A bufs, bf16 128x32)
    __shared__ float4 BsbV[3][512];   // 3 x 8KB  (B bufs, bf16 128x32)
    char* const Asb_b = (char*)AsbV;
    char* const Bsb_b = (char*)BsbV;

    const int tid  = threadIdx.x;
    const int wave = tid >> 6, lane = tid & 63;
    const int wr = wave >> 1, wc = wave & 1;
    const int row0 = blockIdx.y * 128, col0 = blockIdx.x * 128;
    const int l15 = lane & 15, l4 = lane >> 4;

    // A staging: thread t -> row=t>>1, k-half=t&1 (16 f32 each)  [VERIFIED]
    const int st_row = tid >> 1, st_kh = tid & 1;
    const int gr_cl  = min(row0 + st_row, M - 1);
    const float* Abase = A + (size_t)gr_cl * LDA + st_kh * 16;
    const int asw   = (st_row >> 1) & 3;
    const int a_wo0 = st_row * 64 + ((st_kh * 2)     ^ asw) * 16;
    const int a_wo1 = st_row * 64 + ((st_kh * 2 + 1) ^ asw) * 16;

    // fragment read offsets  [VERIFIED]
    int a_off[4], b_off[4];
    #pragma unroll
    for (int mi = 0; mi < 4; ++mi) {
        const int r   = wr * 64 + mi * 16 + l15;
        const int kcp = l4 ^ ((r >> 1) & 3);
        a_off[mi] = r * 64 + kcp * 16;
    }
    #pragma unroll
    for (int ni = 0; ni < 4; ++ni) {
        const int c   = wc * 64 + ni * 16 + l15;
        const int kcp = l4 ^ ((c >> 1) & 3);
        b_off[ni] = c * 64 + kcp * 16;
    }

    // B staging source (source-side swizzle)  [VERIFIED]
    const __bf16* bsrc[2];
    #pragma unroll
    for (int i = 0; i < 2; ++i) {
        const int c   = (wave * 2 + i) * 64 + lane;
        const int col = c >> 2, kcp = c & 3;
        const int kc  = kcp ^ ((col >> 1) & 3);
        bsrc[i] = Wt + (size_t)(col0 + col) * 256 + kc * 8;
    }

    auto issueB = [&](int kt, int bbuf) {
        #pragma unroll
        for (int i = 0; i < 2; ++i)
            load_lds16(bsrc[i] + kt * 32, Bsb_b + bbuf * 8192 + (wave * 2 + i) * 1024);
    };
    auto loadA = [&](int kt, float4* g) {
        const float* ga = Abase + kt * 32;
        g[0] = ((const float4*)ga)[0];
        g[1] = ((const float4*)ga)[1];
        g[2] = ((const float4*)ga)[2];
        g[3] = ((const float4*)ga)[3];
    };
    auto writeA = [&](int abuf, const float4* g) {
        bf16x8 c0, c1;
        c0[0] = (__bf16)g[0].x; c0[1] = (__bf16)g[0].y; c0[2] = (__bf16)g[0].z; c0[3] = (__bf16)g[0].w;
        c0[4] = (__bf16)g[1].x; c0[5] = (__bf16)g[1].y; c0[6] = (__bf16)g[1].z; c0[7] = (__bf16)g[1].w;
        c1[0] = (__bf16)g[2].x; c1[1] = (__bf16)g[2].y; c1[2] = (__bf16)g[2].z; c1[3] = (__bf16)g[2].w;
        c1[4] = (__bf16)g[3].x; c1[5] = (__bf16)g[3].y; c1[6] = (__bf16)g[3].z; c1[7] = (__bf16)g[3].w;
        *(bf16x8*)(Asb_b + abuf * 8192 + a_wo0) = c0;
        *(bf16x8*)(Asb_b + abuf * 8192 + a_wo1) = c1;
    };

    f32x4 acc[4][4] = {};
    float4 g[2][4];

    issueB(0, 0);
    loadA(0, g[0]);
    issueB(1, 1);
    loadA(1, g[1]);
    writeA(0, g[0]);
    WAITLGKM0; BAR; CFENCE; SCHEDB;

    #pragma unroll
    for (int u = 0; u < 8; ++u) {
        if (u + 2 <= 7) {
            loadA(u + 2, g[u & 1]);
            issueB(u + 2, (u + 2) % 3);
        }

        const char* Ab = Asb_b + (u & 1) * 8192;
        const char* Bb = Bsb_b + (u % 3) * 8192;
        bf16x8 a[4], b[4];
        #pragma unroll
        for (int mi = 0; mi < 4; ++mi) a[mi] = *(const bf16x8*)(Ab + a_off[mi]);
        #pragma unroll
        for (int ni = 0; ni < 4; ++ni) b[ni] = *(const bf16x8*)(Bb + b_off[ni]);

        #pragma unroll
        for (int mi = 0; mi < 4; ++mi)
            #pragma unroll
            for (int ni = 0; ni < 4; ++ni)
                acc[mi][ni] = __builtin_amdgcn_mfma_f32_16x16x32_bf16(
                    a[mi], b[ni], acc[mi][ni], 0, 0, 0);

        if (u + 1 <= 7) {
            writeA((u + 1) & 1, g[(u + 1) & 1]);
            WAITLGKM0; BAR; CFENCE; SCHEDB;
        }
    }

    // epilogue
    int   colb[4];
    float bb[4], we0[4], we1[4];
    #pragma unroll
    for (int ni = 0; ni < 4; ++ni) {
        const int c = col0 + wc * 64 + ni * 16 + l15;
        colb[ni] = c;
        bb[ni]   = bias[c];
        if (RELUHI && c >= 256) { we0[ni] = Wex[c - 256]; we1[ni] = Wex[c - 256 + 256]; }
        else                    { we0[ni] = 0.f; we1[ni] = 0.f; }
    }
    #pragma unroll
    for (int mi = 0; mi < 4; ++mi) {
        #pragma unroll
        for (int rr = 0; rr < 4; ++rr) {
            const int row = row0 + wr * 64 + mi * 16 + l4 * 4 + rr;
            if (row >= M) continue;
            float e0 = 0.f, e1 = 0.f;
            if (RELUHI) { e0 = extra[(size_t)row * 2]; e1 = extra[(size_t)row * 2 + 1]; }
            #pragma unroll
            for (int ni = 0; ni < 4; ++ni) {
                float v = acc[mi][ni][rr] + bb[ni];
                if (RELUHI && colb[ni] >= 256) {
                    v += e0 * we0[ni] + e1 * we1[ni];
                    v = fmaxf(v, 0.f);
                }
                if (OUTBF16) ((__bf16*)outp)[(size_t)row * N + colb[ni]] = (__bf16)v;
                else         ((float*)outp)[(size_t)row * N + colb[ni]]  = v;
            }
        }
    }
}

// ---------------------------------------------------------------------------
// Fused: softmax (spec cancels) + locations + VECTORIZED bilinear sampling.
// One block per (b,q), 256 threads.
// Sampling lane map: tid = h*32 + (sp*4 + cq): 8 samples in flight (sp) x
// 4 channel-quads (cq, 8 channels each as bf16x8 16B loads). attn*w*valid
// folded into corner weight; shfl_xor(4/8/16) reduces over sp.
// ---------------------------------------------------------------------------
__global__ __launch_bounds__(256)
void attn_sample_kernel(const float* __restrict__ axyhid,
                        const float* __restrict__ refp, const float* __restrict__ objs,
                        const float* __restrict__ off, const __bf16* __restrict__ v,
                        float* __restrict__ agg)
{
    const int bq = blockIdx.x;
    const int b  = bq / Q_;
    const int tid = threadIdx.x;

    __shared__ float sm[128];
    __shared__ float sa[128];
    __shared__ float sl[256];

    if (tid < 128)
        sm[tid] = axyhid[(size_t)bq * 512 + tid] * axyhid[(size_t)bq * 512 + 128 + tid];
    __syncthreads();

    if (tid < 128) {
        const int hh = tid >> 4;
        float mx = -1e30f;
        #pragma unroll
        for (int i = 0; i < 16; ++i) mx = fmaxf(mx, sm[hh * 16 + i]);
        float s = 0.f;
        #pragma unroll
        for (int i = 0; i < 16; ++i) s += __expf(sm[hh * 16 + i] - mx);
        sa[tid] = __expf(sm[tid] - mx) / s;

        const int l = (tid >> 2) & 3;
        const float os0 = objs[(size_t)bq * 2], os1 = objs[(size_t)bq * 2 + 1];
        const float r0 = refp[((size_t)bq * 4 + l) * 2];
        const float r1 = refp[((size_t)bq * 4 + l) * 2 + 1];
        const float o0 = off[(size_t)bq * 256 + tid * 2]     * os0;
        const float o1 = off[(size_t)bq * 256 + tid * 2 + 1] * os1;
        sl[tid * 2]     = fminf(fmaxf(r0 + o0, 0.f), 1.f);
        sl[tid * 2 + 1] = fminf(fmaxf(r1 + o1, 0.f), 1.f);
    }
    __syncthreads();

    // ---- vectorized sampling phase ----
    const int h = tid >> 5, lane32 = tid & 31;
    const int sp = lane32 >> 2, cq = lane32 & 3;
    const int chbase = h * 32 + cq * 8;
    const __bf16* vb = v + (size_t)b * S_ * 256;

    float acc8[8] = {};

    #pragma unroll
    for (int gidx = 0; gidx < 2; ++gidx) {
        const int lp  = gidx * 8 + sp;        // 0..15 within head
        const int li  = h * 16 + lp;
        const int lvl = lp >> 2;
        // level constants via selects (no runtime-indexed arrays)
        const int Wl = (lvl == 0) ? 100 : (lvl == 1) ? 50 : (lvl == 2) ? 25 : 13;
        const int Hl = Wl;
        const int st = (lvl == 0) ? 0 : (lvl == 1) ? 10000 : (lvl == 2) ? 12500 : 13125;

        const float a  = sa[li];
        const float lx = sl[li * 2], ly = sl[li * 2 + 1];
        const float x = lx * (float)Wl - 0.5f;
        const float y = ly * (float)Hl - 0.5f;
        const float x0f = floorf(x), y0f = floorf(y);
        const float fx = x - x0f, fy = y - y0f;
        const int x0 = (int)x0f, y0 = (int)y0f;

        #pragma unroll
        for (int c = 0; c < 4; ++c) {
            const int dx = c & 1, dy = c >> 1;
            const int xi = x0 + dx, yi = y0 + dy;
            const float wgt = (dx ? fx : 1.f - fx) * (dy ? fy : 1.f - fy);
            const bool valid = (xi >= 0) & (xi < Wl) & (yi >= 0) & (yi < Hl);
            const int idx = min(max(yi, 0), Hl - 1) * Wl + min(max(xi, 0), Wl - 1);
            const float wa = valid ? a * wgt : 0.f;
            const bf16x8 gv = *(const bf16x8*)(vb + (size_t)(st + idx) * 256 + chbase);
            #pragma unroll
            for (int j = 0; j < 8; ++j) acc8[j] += wa * (float)gv[j];
        }
    }

    // reduce over sp (lanes differ in bits 2..4)
    #pragma unroll
    for (int m = 4; m <= 16; m <<= 1)
        #pragma unroll
        for (int j = 0; j < 8; ++j)
            acc8[j] += __shfl_xor(acc8[j], m);

    if (sp == 0) {
        #pragma unroll
        for (int j = 0; j < 8; ++j)
            agg[(size_t)bq * 256 + chbase + j] = acc8[j];
    }
}

// ---------------------------------------------------------------------------
extern "C" void kernel_launch(void* const* d_in, const int* in_sizes, int n_in,
                              void* d_out, int out_size, void* d_ws, size_t ws_size,
                              hipStream_t stream)
{
    const float* query = (const float*)d_in[0];
    const float* refp  = (const float*)d_in[1];
    const float* x_in  = (const float*)d_in[2];
    const float* objs  = (const float*)d_in[3];
    const float* w_q    = (const float*)d_in[6];
    const float* b_q    = (const float*)d_in[7];
    const float* w_v    = (const float*)d_in[8];
    const float* b_v    = (const float*)d_in[9];
    const float* w_o    = (const float*)d_in[10];
    const float* b_o    = (const float*)d_in[11];
    const float* w_off1 = (const float*)d_in[12];
    const float* b_off1 = (const float*)d_in[13];
    const float* w_off2 = (const float*)d_in[14];
    const float* b_off2 = (const float*)d_in[15];
    const float* w_ax   = (const float*)d_in[16];
    const float* b_ax   = (const float*)d_in[17];
    const float* w_ay   = (const float*)d_in[18];
    const float* b_ay   = (const float*)d_in[19];

    float* ws = (float*)d_ws;
    float* axyhid_ws = ws;                               // BQ*512 f32
    float* off_ws    = axyhid_ws + (size_t)BQ * 512;     // BQ*256 f32
    float* agg_ws    = off_ws    + (size_t)BQ * 256;     // BQ*256 f32
    float* bcomb_ws  = agg_ws    + (size_t)BQ * 256;     // 512 f32
    __bf16* v_bf    = (__bf16*)(bcomb_ws + 512);         // BS*256 bf16
    __bf16* wt_v    = v_bf    + (size_t)BS * 256;
    __bf16* wt_o    = wt_v    + 256 * 256;
    __bf16* wt_off2 = wt_o    + 256 * 256;
    __bf16* wt_cat  = wt_off2 + 256 * 256;               // 512*256
    __bf16* wcomb   = wt_cat  + 512 * 256;               // 512*256

    const dim3 blk(256);

    // weight prep
    transpose_all<<<320, blk, 0, stream>>>(w_v, w_o, w_off1, w_off2, w_ax, w_ay,
                                           wt_v, wt_o, wt_off2, wt_cat);
    combine_w<<<8, blk, 0, stream>>>(wt_cat, w_q, wcomb);
    combine_bias<<<2, blk, 0, stream>>>(wt_cat, b_q, b_ax, b_ay, b_off1, bcomb_ws);

    // v = x_in @ w_v + b_v -> bf16
    gemm_dp<false, true><<<dim3(2, (BS + 127) / 128), blk, 0, stream>>>(
        x_in, wt_v, b_v, nullptr, nullptr, v_bf, BS, 256, 256);

    // [ax|ay|hid] = query @ Wcomb + bcomb (+obj rank-2 & relu on hid cols)
    gemm_dp<true, false><<<dim3(4, (BQ + 127) / 128), blk, 0, stream>>>(
        query, wcomb, bcomb_ws, objs, w_off1 + 256 * 256, axyhid_ws, BQ, 512, 256);

    // offsets = hid @ w_off2 + b_off2 -> f32
    gemm_dp<false, false><<<dim3(2, (BQ + 127) / 128), blk, 0, stream>>>(
        axyhid_ws + 256, wt_off2, b_off2, nullptr, nullptr, off_ws, BQ, 256, 512);

    // fused softmax/locs/sampling (vectorized gathers)
    attn_sample_kernel<<<BQ, blk, 0, stream>>>(axyhid_ws, refp, objs, off_ws,
                                               v_bf, agg_ws);

    // out = agg @ w_o + b_o -> f32
    gemm_dp<false, false><<<dim3(2, (BQ + 127) / 128), blk, 0, stream>>>(
        agg_ws, wt_o, b_o, nullptr, nullptr, (float*)d_out, BQ, 256, 256);
}

// Round 10
// 113.234 us; speedup vs baseline: 1.9363x; 1.1209x over previous
//
#include <hip/hip_runtime.h>
#include <hip/hip_bf16.h>
#include <math.h>

// Problem constants (from reference)
constexpr int B_ = 8, Q_ = 900;
constexpr int S_ = 13294;
constexpr int BQ = 7200;     // B*Q
constexpr int BS = 106352;   // B*S

typedef __bf16 bf16x8 __attribute__((ext_vector_type(8)));
typedef float  f32x4  __attribute__((ext_vector_type(4)));

#define WAITLGKM0 asm volatile("s_waitcnt lgkmcnt(0)" ::: "memory")
#define SCHEDB    __builtin_amdgcn_sched_barrier(0)
#define BAR       __builtin_amdgcn_s_barrier()
#define CFENCE    asm volatile("" ::: "memory")

__device__ __forceinline__ void load_lds16(const void* g, void* lds) {
    __builtin_amdgcn_global_load_lds(
        (const __attribute__((address_space(1))) void*)g,
        (__attribute__((address_space(3))) void*)lds, 16, 0, 0);
}

// ---------------------------------------------------------------------------
// Fused transpose+cast of weights into bf16 [N][K=256] layouts.
// ---------------------------------------------------------------------------
__global__ __launch_bounds__(256)
void transpose_all(const float* __restrict__ wv, const float* __restrict__ wo,
                   const float* __restrict__ woff1, const float* __restrict__ woff2,
                   const float* __restrict__ wax, const float* __restrict__ way,
                   __bf16* __restrict__ tv, __bf16* __restrict__ to_,
                   __bf16* __restrict__ toff2, __bf16* __restrict__ tcat)
{
    const int bi = blockIdx.x;
    __shared__ float tile[32][33];
    const int tx = threadIdx.x & 31, ty = threadIdx.x >> 5;

    const float* src; __bf16* dst; int k0, n0, scol, sN = 256;
    if (bi < 192) {
        const int wid = bi >> 6, t = bi & 63;
        k0 = (t & 7) * 32; n0 = (t >> 3) * 32; scol = n0;
        if      (wid == 0) { src = wv;    dst = tv;    }
        else if (wid == 1) { src = wo;    dst = to_;   }
        else               { src = woff2; dst = toff2; }
    } else {
        const int t = bi - 192;
        k0 = (t & 7) * 32; n0 = (t >> 3) * 32;
        dst = tcat;
        if      (n0 < 128) { src = wax;   scol = n0;       sN = 128; }
        else if (n0 < 256) { src = way;   scol = n0 - 128; sN = 128; }
        else               { src = woff1; scol = n0 - 256; sN = 256; }
    }

    #pragma unroll
    for (int i = 0; i < 4; ++i)
        tile[ty + 8 * i][tx] = src[(size_t)(k0 + ty + 8 * i) * sN + scol + tx];
    __syncthreads();
    #pragma unroll
    for (int i = 0; i < 4; ++i)
        dst[(size_t)(n0 + ty + 8 * i) * 256 + k0 + tx] = (__bf16)tile[tx][ty + 8 * i];
}

// ---------------------------------------------------------------------------
// Wcomb[n][k] = sum_c tcat[n][c] * wq[k][c]   (512x256x256, bf16 out)
// ---------------------------------------------------------------------------
__global__ __launch_bounds__(256)
void combine_w(const __bf16* __restrict__ tcat, const float* __restrict__ wq,
               __bf16* __restrict__ wcomb)
{
    const int wid  = (blockIdx.x << 2) + (threadIdx.x >> 6);
    const int lane = threadIdx.x & 63;
    const int n0 = (wid >> 2) * 64, k0 = (wid & 3) * 64;
    const int l15 = lane & 15, l4 = lane >> 4;

    f32x4 acc[4][4] = {};
    #pragma unroll
    for (int s = 0; s < 8; ++s) {
        const int c0 = s * 32 + l4 * 8;
        bf16x8 am[4], bm[4];
        #pragma unroll
        for (int mi = 0; mi < 4; ++mi)
            am[mi] = *(const bf16x8*)(tcat + (size_t)(n0 + mi * 16 + l15) * 256 + c0);
        #pragma unroll
        for (int ni = 0; ni < 4; ++ni) {
            const float* wr_ = wq + (size_t)(k0 + ni * 16 + l15) * 256 + c0;
            const float4 f0 = ((const float4*)wr_)[0];
            const float4 f1 = ((const float4*)wr_)[1];
            bm[ni][0] = (__bf16)f0.x; bm[ni][1] = (__bf16)f0.y;
            bm[ni][2] = (__bf16)f0.z; bm[ni][3] = (__bf16)f0.w;
            bm[ni][4] = (__bf16)f1.x; bm[ni][5] = (__bf16)f1.y;
            bm[ni][6] = (__bf16)f1.z; bm[ni][7] = (__bf16)f1.w;
        }
        #pragma unroll
        for (int mi = 0; mi < 4; ++mi)
            #pragma unroll
            for (int ni = 0; ni < 4; ++ni)
                acc[mi][ni] = __builtin_amdgcn_mfma_f32_16x16x32_bf16(
                    am[mi], bm[ni], acc[mi][ni], 0, 0, 0);
    }
    #pragma unroll
    for (int mi = 0; mi < 4; ++mi)
        #pragma unroll
        for (int rr = 0; rr < 4; ++rr) {
            const int n = n0 + mi * 16 + l4 * 4 + rr;
            #pragma unroll
            for (int ni = 0; ni < 4; ++ni)
                wcomb[(size_t)n * 256 + k0 + ni * 16 + l15] = (__bf16)acc[mi][ni][rr];
        }
}

// bcomb[n] = sum_c b_q[c]*tcat[n][c] + (n<128? b_ax[n] : n<256? b_ay[n-128] : b_off1[n-256])
__global__ __launch_bounds__(256)
void combine_bias(const __bf16* __restrict__ tcat, const float* __restrict__ bq,
                  const float* __restrict__ bax, const float* __restrict__ bay,
                  const float* __restrict__ boff1, float* __restrict__ bcomb)
{
    const int n = blockIdx.x * 256 + threadIdx.x;
    float acc = (n < 128) ? bax[n] : (n < 256 ? bay[n - 128] : boff1[n - 256]);
    const __bf16* row = tcat + (size_t)n * 256;
    #pragma unroll 4
    for (int c8 = 0; c8 < 32; ++c8) {
        const bf16x8 rv = *(const bf16x8*)(row + c8 * 8);
        #pragma unroll
        for (int j = 0; j < 8; ++j) acc += bq[c8 * 8 + j] * (float)rv[j];
    }
    bcomb[n] = acc;
}

// ---------------------------------------------------------------------------
// 8-wave 128x256 deep-pipelined v-GEMM: v[M,256](bf16) = A[M,256](f32)@Wt+b.
// 512 threads = 8 waves (2 rows x 4 cols of 64x64). BK=32, 8 K-steps.
// A: reg-staged 2-deep (thread t -> row=t>>2, k-octet=t&3, one 16B chunk,
//    swizzle chunk = kq ^ ((row>>1)&3) — same verified XOR family).
// B: global_load_lds, 3 x 16KB buffers, verified chunk mapping (1024 chunks).
// LDS = 2x8KB + 3x16KB = 64KB -> 2 blocks/CU = 16 waves/CU.
// ---------------------------------------------------------------------------
__global__ __launch_bounds__(512)
void gemm_v8(const float* __restrict__ A, const __bf16* __restrict__ Wt,
             const float* __restrict__ bias, __bf16* __restrict__ outp, int M)
{
    __shared__ float4 AsbV[2][512];    // 2 x 8KB  (A bufs, bf16 128x32)
    __shared__ float4 BsbV[3][1024];   // 3 x 16KB (B bufs, bf16 256x32)
    char* const Asb_b = (char*)AsbV;
    char* const Bsb_b = (char*)BsbV;

    const int tid  = threadIdx.x;
    const int wave = tid >> 6, lane = tid & 63;
    const int wr = wave >> 2, wc = wave & 3;    // 2x4 wave grid
    const int row0 = blockIdx.x * 128;
    const int l15 = lane & 15, l4 = lane >> 4;

    // A staging: thread t -> row = t>>2, k-octet kq = t&3 (8 f32 = 2 float4)
    const int st_row = tid >> 2, st_kq = tid & 3;
    const int gr_cl  = min(row0 + st_row, M - 1);
    const float* Abase = A + (size_t)gr_cl * 256 + st_kq * 8;
    const int a_wo = st_row * 64 + ((st_kq ^ ((st_row >> 1) & 3)) * 16);

    // fragment read offsets (verified formulas)
    int a_off[4], b_off[4];
    #pragma unroll
    for (int mi = 0; mi < 4; ++mi) {
        const int r = wr * 64 + mi * 16 + l15;
        a_off[mi] = r * 64 + (l4 ^ ((r >> 1) & 3)) * 16;
    }
    #pragma unroll
    for (int ni = 0; ni < 4; ++ni) {
        const int c = wc * 64 + ni * 16 + l15;
        b_off[ni] = c * 64 + (l4 ^ ((c >> 1) & 3)) * 16;
    }

    // B staging source (verified chunk mapping, 1024 chunks over 8 waves x 2)
    const __bf16* bsrc[2];
    #pragma unroll
    for (int i = 0; i < 2; ++i) {
        const int c   = (wave * 2 + i) * 64 + lane;      // 0..1023
        const int col = c >> 2, kcp = c & 3;
        const int kc  = kcp ^ ((col >> 1) & 3);
        bsrc[i] = Wt + (size_t)col * 256 + kc * 8;
    }

    auto issueB = [&](int kt, int bbuf) {
        #pragma unroll
        for (int i = 0; i < 2; ++i)
            load_lds16(bsrc[i] + kt * 32, Bsb_b + bbuf * 16384 + (wave * 2 + i) * 1024);
    };
    auto loadA = [&](int kt, float4* g) {
        const float* ga = Abase + kt * 32;
        g[0] = ((const float4*)ga)[0];
        g[1] = ((const float4*)ga)[1];
    };
    auto writeA = [&](int abuf, const float4* g) {
        bf16x8 c0;
        c0[0] = (__bf16)g[0].x; c0[1] = (__bf16)g[0].y; c0[2] = (__bf16)g[0].z; c0[3] = (__bf16)g[0].w;
        c0[4] = (__bf16)g[1].x; c0[5] = (__bf16)g[1].y; c0[6] = (__bf16)g[1].z; c0[7] = (__bf16)g[1].w;
        *(bf16x8*)(Asb_b + abuf * 8192 + a_wo) = c0;
    };

    f32x4 acc[4][4] = {};
    float4 g[2][2];

    issueB(0, 0);
    loadA(0, g[0]);
    issueB(1, 1);
    loadA(1, g[1]);
    writeA(0, g[0]);
    WAITLGKM0; BAR; CFENCE; SCHEDB;

    #pragma unroll
    for (int u = 0; u < 8; ++u) {
        if (u + 2 <= 7) {
            loadA(u + 2, g[u & 1]);
            issueB(u + 2, (u + 2) % 3);
        }

        const char* Ab = Asb_b + (u & 1) * 8192;
        const char* Bb = Bsb_b + (u % 3) * 16384;
        bf16x8 a[4], b[4];
        #pragma unroll
        for (int mi = 0; mi < 4; ++mi) a[mi] = *(const bf16x8*)(Ab + a_off[mi]);
        #pragma unroll
        for (int ni = 0; ni < 4; ++ni) b[ni] = *(const bf16x8*)(Bb + b_off[ni]);

        #pragma unroll
        for (int mi = 0; mi < 4; ++mi)
            #pragma unroll
            for (int ni = 0; ni < 4; ++ni)
                acc[mi][ni] = __builtin_amdgcn_mfma_f32_16x16x32_bf16(
                    a[mi], b[ni], acc[mi][ni], 0, 0, 0);

        if (u + 1 <= 7) {
            writeA((u + 1) & 1, g[(u + 1) & 1]);
            WAITLGKM0; BAR; CFENCE; SCHEDB;
        }
    }

    // epilogue: bf16 store, 64x64 per wave at (wr*64, wc*64)
    float bb[4];
    #pragma unroll
    for (int ni = 0; ni < 4; ++ni) bb[ni] = bias[wc * 64 + ni * 16 + l15];
    #pragma unroll
    for (int mi = 0; mi < 4; ++mi) {
        #pragma unroll
        for (int rr = 0; rr < 4; ++rr) {
            const int row = row0 + wr * 64 + mi * 16 + l4 * 4 + rr;
            if (row >= M) continue;
            #pragma unroll
            for (int ni = 0; ni < 4; ++ni)
                outp[(size_t)row * 256 + wc * 64 + ni * 16 + l15] =
                    (__bf16)(acc[mi][ni][rr] + bb[ni]);
        }
    }
}

// ---------------------------------------------------------------------------
// Deep-pipelined bf16 MFMA GEMM, 4-wave 128x128 (verified R8) — small GEMMs.
// ---------------------------------------------------------------------------
template<bool RELUHI, bool OUTBF16>
__global__ __launch_bounds__(256)
void gemm_dp(const float* __restrict__ A, const __bf16* __restrict__ Wt,
             const float* __restrict__ bias, const float* __restrict__ extra,
             const float* __restrict__ Wex, void* __restrict__ outp,
             int M, int N, int LDA)
{
    __shared__ float4 AsbV[2][512];
    __shared__ float4 BsbV[3][512];
    char* const Asb_b = (char*)AsbV;
    char* const Bsb_b = (char*)BsbV;

    const int tid  = threadIdx.x;
    const int wave = tid >> 6, lane = tid & 63;
    const int wr = wave >> 1, wc = wave & 1;
    const int row0 = blockIdx.y * 128, col0 = blockIdx.x * 128;
    const int l15 = lane & 15, l4 = lane >> 4;

    const int st_row = tid >> 1, st_kh = tid & 1;
    const int gr_cl  = min(row0 + st_row, M - 1);
    const float* Abase = A + (size_t)gr_cl * LDA + st_kh * 16;
    const int asw   = (st_row >> 1) & 3;
    const int a_wo0 = st_row * 64 + ((st_kh * 2)     ^ asw) * 16;
    const int a_wo1 = st_row * 64 + ((st_kh * 2 + 1) ^ asw) * 16;

    int a_off[4], b_off[4];
    #pragma unroll
    for (int mi = 0; mi < 4; ++mi) {
        const int r   = wr * 64 + mi * 16 + l15;
        a_off[mi] = r * 64 + (l4 ^ ((r >> 1) & 3)) * 16;
    }
    #pragma unroll
    for (int ni = 0; ni < 4; ++ni) {
        const int c   = wc * 64 + ni * 16 + l15;
        b_off[ni] = c * 64 + (l4 ^ ((c >> 1) & 3)) * 16;
    }

    const __bf16* bsrc[2];
    #pragma unroll
    for (int i = 0; i < 2; ++i) {
        const int c   = (wave * 2 + i) * 64 + lane;
        const int col = c >> 2, kcp = c & 3;
        const int kc  = kcp ^ ((col >> 1) & 3);
        bsrc[i] = Wt + (size_t)(col0 + col) * 256 + kc * 8;
    }

    auto issueB = [&](int kt, int bbuf) {
        #pragma unroll
        for (int i = 0; i < 2; ++i)
            load_lds16(bsrc[i] + kt * 32, Bsb_b + bbuf * 8192 + (wave * 2 + i) * 1024);
    };
    auto loadA = [&](int kt, float4* g) {
        const float* ga = Abase + kt * 32;
        g[0] = ((const float4*)ga)[0];
        g[1] = ((const float4*)ga)[1];
        g[2] = ((const float4*)ga)[2];
        g[3] = ((const float4*)ga)[3];
    };
    auto writeA = [&](int abuf, const float4* g) {
        bf16x8 c0, c1;
        c0[0] = (__bf16)g[0].x; c0[1] = (__bf16)g[0].y; c0[2] = (__bf16)g[0].z; c0[3] = (__bf16)g[0].w;
        c0[4] = (__bf16)g[1].x; c0[5] = (__bf16)g[1].y; c0[6] = (__bf16)g[1].z; c0[7] = (__bf16)g[1].w;
        c1[0] = (__bf16)g[2].x; c1[1] = (__bf16)g[2].y; c1[2] = (__bf16)g[2].z; c1[3] = (__bf16)g[2].w;
        c1[4] = (__bf16)g[3].x; c1[5] = (__bf16)g[3].y; c1[6] = (__bf16)g[3].z; c1[7] = (__bf16)g[3].w;
        *(bf16x8*)(Asb_b + abuf * 8192 + a_wo0) = c0;
        *(bf16x8*)(Asb_b + abuf * 8192 + a_wo1) = c1;
    };

    f32x4 acc[4][4] = {};
    float4 g[2][4];

    issueB(0, 0);
    loadA(0, g[0]);
    issueB(1, 1);
    loadA(1, g[1]);
    writeA(0, g[0]);
    WAITLGKM0; BAR; CFENCE; SCHEDB;

    #pragma unroll
    for (int u = 0; u < 8; ++u) {
        if (u + 2 <= 7) {
            loadA(u + 2, g[u & 1]);
            issueB(u + 2, (u + 2) % 3);
        }

        const char* Ab = Asb_b + (u & 1) * 8192;
        const char* Bb = Bsb_b + (u % 3) * 8192;
        bf16x8 a[4], b[4];
        #pragma unroll
        for (int mi = 0; mi < 4; ++mi) a[mi] = *(const bf16x8*)(Ab + a_off[mi]);
        #pragma unroll
        for (int ni = 0; ni < 4; ++ni) b[ni] = *(const bf16x8*)(Bb + b_off[ni]);

        #pragma unroll
        for (int mi = 0; mi < 4; ++mi)
            #pragma unroll
            for (int ni = 0; ni < 4; ++ni)
                acc[mi][ni] = __builtin_amdgcn_mfma_f32_16x16x32_bf16(
                    a[mi], b[ni], acc[mi][ni], 0, 0, 0);

        if (u + 1 <= 7) {
            writeA((u + 1) & 1, g[(u + 1) & 1]);
            WAITLGKM0; BAR; CFENCE; SCHEDB;
        }
    }

    int   colb[4];
    float bb[4], we0[4], we1[4];
    #pragma unroll
    for (int ni = 0; ni < 4; ++ni) {
        const int c = col0 + wc * 64 + ni * 16 + l15;
        colb[ni] = c;
        bb[ni]   = bias[c];
        if (RELUHI && c >= 256) { we0[ni] = Wex[c - 256]; we1[ni] = Wex[c - 256 + 256]; }
        else                    { we0[ni] = 0.f; we1[ni] = 0.f; }
    }
    #pragma unroll
    for (int mi = 0; mi < 4; ++mi) {
        #pragma unroll
        for (int rr = 0; rr < 4; ++rr) {
            const int row = row0 + wr * 64 + mi * 16 + l4 * 4 + rr;
            if (row >= M) continue;
            float e0 = 0.f, e1 = 0.f;
            if (RELUHI) { e0 = extra[(size_t)row * 2]; e1 = extra[(size_t)row * 2 + 1]; }
            #pragma unroll
            for (int ni = 0; ni < 4; ++ni) {
                float v = acc[mi][ni][rr] + bb[ni];
                if (RELUHI && colb[ni] >= 256) {
                    v += e0 * we0[ni] + e1 * we1[ni];
                    v = fmaxf(v, 0.f);
                }
                if (OUTBF16) ((__bf16*)outp)[(size_t)row * N + colb[ni]] = (__bf16)v;
                else         ((float*)outp)[(size_t)row * N + colb[ni]]  = v;
            }
        }
    }
}

// ---------------------------------------------------------------------------
// Fused: softmax (spec cancels) + locations + VECTORIZED bilinear sampling.
// ---------------------------------------------------------------------------
__global__ __launch_bounds__(256)
void attn_sample_kernel(const float* __restrict__ axyhid,
                        const float* __restrict__ refp, const float* __restrict__ objs,
                        const float* __restrict__ off, const __bf16* __restrict__ v,
                        float* __restrict__ agg)
{
    const int bq = blockIdx.x;
    const int b  = bq / Q_;
    const int tid = threadIdx.x;

    __shared__ float sm[128];
    __shared__ float sa[128];
    __shared__ float sl[256];

    if (tid < 128)
        sm[tid] = axyhid[(size_t)bq * 512 + tid] * axyhid[(size_t)bq * 512 + 128 + tid];
    __syncthreads();

    if (tid < 128) {
        const int hh = tid >> 4;
        float mx = -1e30f;
        #pragma unroll
        for (int i = 0; i < 16; ++i) mx = fmaxf(mx, sm[hh * 16 + i]);
        float s = 0.f;
        #pragma unroll
        for (int i = 0; i < 16; ++i) s += __expf(sm[hh * 16 + i] - mx);
        sa[tid] = __expf(sm[tid] - mx) / s;

        const int l = (tid >> 2) & 3;
        const float os0 = objs[(size_t)bq * 2], os1 = objs[(size_t)bq * 2 + 1];
        const float r0 = refp[((size_t)bq * 4 + l) * 2];
        const float r1 = refp[((size_t)bq * 4 + l) * 2 + 1];
        const float o0 = off[(size_t)bq * 256 + tid * 2]     * os0;
        const float o1 = off[(size_t)bq * 256 + tid * 2 + 1] * os1;
        sl[tid * 2]     = fminf(fmaxf(r0 + o0, 0.f), 1.f);
        sl[tid * 2 + 1] = fminf(fmaxf(r1 + o1, 0.f), 1.f);
    }
    __syncthreads();

    const int h = tid >> 5, lane32 = tid & 31;
    const int sp = lane32 >> 2, cq = lane32 & 3;
    const int chbase = h * 32 + cq * 8;
    const __bf16* vb = v + (size_t)b * S_ * 256;

    float acc8[8] = {};

    #pragma unroll
    for (int gidx = 0; gidx < 2; ++gidx) {
        const int lp  = gidx * 8 + sp;
        const int li  = h * 16 + lp;
        const int lvl = lp >> 2;
        const int Wl = (lvl == 0) ? 100 : (lvl == 1) ? 50 : (lvl == 2) ? 25 : 13;
        const int Hl = Wl;
        const int st = (lvl == 0) ? 0 : (lvl == 1) ? 10000 : (lvl == 2) ? 12500 : 13125;

        const float a  = sa[li];
        const float lx = sl[li * 2], ly = sl[li * 2 + 1];
        const float x = lx * (float)Wl - 0.5f;
        const float y = ly * (float)Hl - 0.5f;
        const float x0f = floorf(x), y0f = floorf(y);
        const float fx = x - x0f, fy = y - y0f;
        const int x0 = (int)x0f, y0 = (int)y0f;

        #pragma unroll
        for (int c = 0; c < 4; ++c) {
            const int dx = c & 1, dy = c >> 1;
            const int xi = x0 + dx, yi = y0 + dy;
            const float wgt = (dx ? fx : 1.f - fx) * (dy ? fy : 1.f - fy);
            const bool valid = (xi >= 0) & (xi < Wl) & (yi >= 0) & (yi < Hl);
            const int idx = min(max(yi, 0), Hl - 1) * Wl + min(max(xi, 0), Wl - 1);
            const float wa = valid ? a * wgt : 0.f;
            const bf16x8 gv = *(const bf16x8*)(vb + (size_t)(st + idx) * 256 + chbase);
            #pragma unroll
            for (int j = 0; j < 8; ++j) acc8[j] += wa * (float)gv[j];
        }
    }

    #pragma unroll
    for (int m = 4; m <= 16; m <<= 1)
        #pragma unroll
        for (int j = 0; j < 8; ++j)
            acc8[j] += __shfl_xor(acc8[j], m);

    if (sp == 0) {
        #pragma unroll
        for (int j = 0; j < 8; ++j)
            agg[(size_t)bq * 256 + chbase + j] = acc8[j];
    }
}

// ---------------------------------------------------------------------------
extern "C" void kernel_launch(void* const* d_in, const int* in_sizes, int n_in,
                              void* d_out, int out_size, void* d_ws, size_t ws_size,
                              hipStream_t stream)
{
    const float* query = (const float*)d_in[0];
    const float* refp  = (const float*)d_in[1];
    const float* x_in  = (const float*)d_in[2];
    const float* objs  = (const float*)d_in[3];
    const float* w_q    = (const float*)d_in[6];
    const float* b_q    = (const float*)d_in[7];
    const float* w_v    = (const float*)d_in[8];
    const float* b_v    = (const float*)d_in[9];
    const float* w_o    = (const float*)d_in[10];
    const float* b_o    = (const float*)d_in[11];
    const float* w_off1 = (const float*)d_in[12];
    const float* b_off1 = (const float*)d_in[13];
    const float* w_off2 = (const float*)d_in[14];
    const float* b_off2 = (const float*)d_in[15];
    const float* w_ax   = (const float*)d_in[16];
    const float* b_ax   = (const float*)d_in[17];
    const float* w_ay   = (const float*)d_in[18];
    const float* b_ay   = (const float*)d_in[19];

    float* ws = (float*)d_ws;
    float* axyhid_ws = ws;                               // BQ*512 f32
    float* off_ws    = axyhid_ws + (size_t)BQ * 512;     // BQ*256 f32
    float* agg_ws    = off_ws    + (size_t)BQ * 256;     // BQ*256 f32
    float* bcomb_ws  = agg_ws    + (size_t)BQ * 256;     // 512 f32
    __bf16* v_bf    = (__bf16*)(bcomb_ws + 512);         // BS*256 bf16
    __bf16* wt_v    = v_bf    + (size_t)BS * 256;
    __bf16* wt_o    = wt_v    + 256 * 256;
    __bf16* wt_off2 = wt_o    + 256 * 256;
    __bf16* wt_cat  = wt_off2 + 256 * 256;               // 512*256
    __bf16* wcomb   = wt_cat  + 512 * 256;               // 512*256

    const dim3 blk(256);

    // weight prep
    transpose_all<<<320, blk, 0, stream>>>(w_v, w_o, w_off1, w_off2, w_ax, w_ay,
                                           wt_v, wt_o, wt_off2, wt_cat);
    combine_w<<<8, blk, 0, stream>>>(wt_cat, w_q, wcomb);
    combine_bias<<<2, blk, 0, stream>>>(wt_cat, b_q, b_ax, b_ay, b_off1, bcomb_ws);

    // v = x_in @ w_v + b_v -> bf16  (8-wave 128x256 blocks)
    gemm_v8<<<(BS + 127) / 128, dim3(512), 0, stream>>>(x_in, wt_v, b_v, v_bf, BS);

    // [ax|ay|hid] = query @ Wcomb + bcomb (+obj rank-2 & relu on hid cols)
    gemm_dp<true, false><<<dim3(4, (BQ + 127) / 128), blk, 0, stream>>>(
        query, wcomb, bcomb_ws, objs, w_off1 + 256 * 256, axyhid_ws, BQ, 512, 256);

    // offsets = hid @ w_off2 + b_off2 -> f32
    gemm_dp<false, false><<<dim3(2, (BQ + 127) / 128), blk, 0, stream>>>(
        axyhid_ws + 256, wt_off2, b_off2, nullptr, nullptr, off_ws, BQ, 256, 512);

    // fused softmax/locs/sampling (vectorized gathers)
    attn_sample_kernel<<<BQ, blk, 0, stream>>>(axyhid_ws, refp, objs, off_ws,
                                               v_bf, agg_ws);

    // out = agg @ w_o + b_o -> f32
    gemm_dp<false, false><<<dim3(2, (BQ + 127) / 128), blk, 0, stream>>>(
        agg_ws, wt_o, b_o, nullptr, nullptr, (float*)d_out, BQ, 256, 256);
}

// Round 11
// 106.613 us; speedup vs baseline: 2.0566x; 1.0621x over previous
//
#include <hip/hip_runtime.h>
#include <hip/hip_bf16.h>
#include <math.h>

// Problem constants (from reference)
constexpr int B_ = 8, Q_ = 900;
constexpr int S_ = 13294;
constexpr int BQ = 7200;     // B*Q
constexpr int BS = 106352;   // B*S
constexpr int NVB = 831;     // v-path blocks = ceil(BS/128)

typedef __bf16 bf16x8 __attribute__((ext_vector_type(8)));
typedef float  f32x4  __attribute__((ext_vector_type(4)));

#define WAITLGKM0 asm volatile("s_waitcnt lgkmcnt(0)" ::: "memory")
#define SCHEDB    __builtin_amdgcn_sched_barrier(0)
#define BAR       __builtin_amdgcn_s_barrier()
#define CFENCE    asm volatile("" ::: "memory")

__device__ __forceinline__ void load_lds16(const void* g, void* lds) {
    __builtin_amdgcn_global_load_lds(
        (const __attribute__((address_space(1))) void*)g,
        (__attribute__((address_space(3))) void*)lds, 16, 0, 0);
}

// ---------------------------------------------------------------------------
// Fused transpose+cast of weights into bf16 [N][K=256] layouts.
// ---------------------------------------------------------------------------
__global__ __launch_bounds__(256)
void transpose_all(const float* __restrict__ wv, const float* __restrict__ wo,
                   const float* __restrict__ woff1, const float* __restrict__ woff2,
                   const float* __restrict__ wax, const float* __restrict__ way,
                   __bf16* __restrict__ tv, __bf16* __restrict__ to_,
                   __bf16* __restrict__ toff2, __bf16* __restrict__ tcat)
{
    const int bi = blockIdx.x;
    __shared__ float tile[32][33];
    const int tx = threadIdx.x & 31, ty = threadIdx.x >> 5;

    const float* src; __bf16* dst; int k0, n0, scol, sN = 256;
    if (bi < 192) {
        const int wid = bi >> 6, t = bi & 63;
        k0 = (t & 7) * 32; n0 = (t >> 3) * 32; scol = n0;
        if      (wid == 0) { src = wv;    dst = tv;    }
        else if (wid == 1) { src = wo;    dst = to_;   }
        else               { src = woff2; dst = toff2; }
    } else {
        const int t = bi - 192;
        k0 = (t & 7) * 32; n0 = (t >> 3) * 32;
        dst = tcat;
        if      (n0 < 128) { src = wax;   scol = n0;       sN = 128; }
        else if (n0 < 256) { src = way;   scol = n0 - 128; sN = 128; }
        else               { src = woff1; scol = n0 - 256; sN = 256; }
    }

    #pragma unroll
    for (int i = 0; i < 4; ++i)
        tile[ty + 8 * i][tx] = src[(size_t)(k0 + ty + 8 * i) * sN + scol + tx];
    __syncthreads();
    #pragma unroll
    for (int i = 0; i < 4; ++i)
        dst[(size_t)(n0 + ty + 8 * i) * 256 + k0 + tx] = (__bf16)tile[tx][ty + 8 * i];
}

// ---------------------------------------------------------------------------
// Merged: blocks 0..7 -> Wcomb[n][k] = sum_c tcat[n][c]*wq[k][c] (bf16 out)
//         blocks 8..9 -> bcomb[n]
// ---------------------------------------------------------------------------
__global__ __launch_bounds__(256)
void combine2(const __bf16* __restrict__ tcat, const float* __restrict__ wq,
              const float* __restrict__ bq, const float* __restrict__ bax,
              const float* __restrict__ bay, const float* __restrict__ boff1,
              __bf16* __restrict__ wcomb, float* __restrict__ bcomb)
{
    const int bi = blockIdx.x;
    if (bi >= 8) {
        const int n = (bi - 8) * 256 + threadIdx.x;
        float acc = (n < 128) ? bax[n] : (n < 256 ? bay[n - 128] : boff1[n - 256]);
        const __bf16* row = tcat + (size_t)n * 256;
        #pragma unroll 4
        for (int c8 = 0; c8 < 32; ++c8) {
            const bf16x8 rv = *(const bf16x8*)(row + c8 * 8);
            #pragma unroll
            for (int j = 0; j < 8; ++j) acc += bq[c8 * 8 + j] * (float)rv[j];
        }
        bcomb[n] = acc;
        return;
    }

    const int wid  = (bi << 2) + (threadIdx.x >> 6);
    const int lane = threadIdx.x & 63;
    const int n0 = (wid >> 2) * 64, k0 = (wid & 3) * 64;
    const int l15 = lane & 15, l4 = lane >> 4;

    f32x4 acc[4][4] = {};
    #pragma unroll
    for (int s = 0; s < 8; ++s) {
        const int c0 = s * 32 + l4 * 8;
        bf16x8 am[4], bm[4];
        #pragma unroll
        for (int mi = 0; mi < 4; ++mi)
            am[mi] = *(const bf16x8*)(tcat + (size_t)(n0 + mi * 16 + l15) * 256 + c0);
        #pragma unroll
        for (int ni = 0; ni < 4; ++ni) {
            const float* wr_ = wq + (size_t)(k0 + ni * 16 + l15) * 256 + c0;
            const float4 f0 = ((const float4*)wr_)[0];
            const float4 f1 = ((const float4*)wr_)[1];
            bm[ni][0] = (__bf16)f0.x; bm[ni][1] = (__bf16)f0.y;
            bm[ni][2] = (__bf16)f0.z; bm[ni][3] = (__bf16)f0.w;
            bm[ni][4] = (__bf16)f1.x; bm[ni][5] = (__bf16)f1.y;
            bm[ni][6] = (__bf16)f1.z; bm[ni][7] = (__bf16)f1.w;
        }
        #pragma unroll
        for (int mi = 0; mi < 4; ++mi)
            #pragma unroll
            for (int ni = 0; ni < 4; ++ni)
                acc[mi][ni] = __builtin_amdgcn_mfma_f32_16x16x32_bf16(
                    am[mi], bm[ni], acc[mi][ni], 0, 0, 0);
    }
    #pragma unroll
    for (int mi = 0; mi < 4; ++mi)
        #pragma unroll
        for (int rr = 0; rr < 4; ++rr) {
            const int n = n0 + mi * 16 + l4 * 4 + rr;
            #pragma unroll
            for (int ni = 0; ni < 4; ++ni)
                wcomb[(size_t)n * 256 + k0 + ni * 16 + l15] = (__bf16)acc[mi][ni][rr];
        }
}

// ---------------------------------------------------------------------------
// Fused main GEMM (512 thr, 8 waves, 128x256 tile, pipeline = verified R10):
//  blocks [0, NVB)      : v = x_in @ wt_v + b_v          -> bf16 v_bf
//  blocks [NVB, NVB+114): axyhid = query @ wcomb + bcomb -> f32 (relu/rank2 on
//                         col-half 1 = hid). 2 blocks per 128-row chunk.
// Identical inner loop / staging / swizzles to R10's gemm_v8 [VERIFIED].
// ---------------------------------------------------------------------------
__global__ __launch_bounds__(512)
void main_fused(const float* __restrict__ x_in, const __bf16* __restrict__ wt_v,
                const float* __restrict__ b_v, __bf16* __restrict__ v_bf,
                const float* __restrict__ query, const __bf16* __restrict__ wcomb,
                const float* __restrict__ bcomb, const float* __restrict__ objs,
                const float* __restrict__ wex, float* __restrict__ axyhid)
{
    __shared__ float4 AsbV[2][512];    // 2 x 8KB
    __shared__ float4 BsbV[3][1024];   // 3 x 16KB
    char* const Asb_b = (char*)AsbV;
    char* const Bsb_b = (char*)BsbV;

    const int bid  = blockIdx.x;
    const bool isV = (bid < NVB);
    const int qb   = bid - NVB;
    const int colhalf = isV ? 0 : (qb & 1);

    const float*  A    = isV ? x_in : query;
    const __bf16* Wt   = isV ? wt_v : (wcomb + (size_t)colhalf * 256 * 256);
    const float*  bias = isV ? b_v  : (bcomb + colhalf * 256);
    const int     M    = isV ? BS   : BQ;
    const int     row0 = isV ? bid * 128 : (qb >> 1) * 128;

    const int tid  = threadIdx.x;
    const int wave = tid >> 6, lane = tid & 63;
    const int wr = wave >> 2, wc = wave & 3;    // 2x4 wave grid
    const int l15 = lane & 15, l4 = lane >> 4;

    // A staging: thread t -> row = t>>2, k-octet kq = t&3  [VERIFIED]
    const int st_row = tid >> 2, st_kq = tid & 3;
    const int gr_cl  = min(row0 + st_row, M - 1);
    const float* Abase = A + (size_t)gr_cl * 256 + st_kq * 8;
    const int a_wo = st_row * 64 + ((st_kq ^ ((st_row >> 1) & 3)) * 16);

    int a_off[4], b_off[4];
    #pragma unroll
    for (int mi = 0; mi < 4; ++mi) {
        const int r = wr * 64 + mi * 16 + l15;
        a_off[mi] = r * 64 + (l4 ^ ((r >> 1) & 3)) * 16;
    }
    #pragma unroll
    for (int ni = 0; ni < 4; ++ni) {
        const int c = wc * 64 + ni * 16 + l15;
        b_off[ni] = c * 64 + (l4 ^ ((c >> 1) & 3)) * 16;
    }

    const __bf16* bsrc[2];
    #pragma unroll
    for (int i = 0; i < 2; ++i) {
        const int c   = (wave * 2 + i) * 64 + lane;      // 0..1023
        const int col = c >> 2, kcp = c & 3;
        const int kc  = kcp ^ ((col >> 1) & 3);
        bsrc[i] = Wt + (size_t)col * 256 + kc * 8;
    }

    auto issueB = [&](int kt, int bbuf) {
        #pragma unroll
        for (int i = 0; i < 2; ++i)
            load_lds16(bsrc[i] + kt * 32, Bsb_b + bbuf * 16384 + (wave * 2 + i) * 1024);
    };
    auto loadA = [&](int kt, float4* g) {
        const float* ga = Abase + kt * 32;
        g[0] = ((const float4*)ga)[0];
        g[1] = ((const float4*)ga)[1];
    };
    auto writeA = [&](int abuf, const float4* g) {
        bf16x8 c0;
        c0[0] = (__bf16)g[0].x; c0[1] = (__bf16)g[0].y; c0[2] = (__bf16)g[0].z; c0[3] = (__bf16)g[0].w;
        c0[4] = (__bf16)g[1].x; c0[5] = (__bf16)g[1].y; c0[6] = (__bf16)g[1].z; c0[7] = (__bf16)g[1].w;
        *(bf16x8*)(Asb_b + abuf * 8192 + a_wo) = c0;
    };

    f32x4 acc[4][4] = {};
    float4 g[2][2];

    issueB(0, 0);
    loadA(0, g[0]);
    issueB(1, 1);
    loadA(1, g[1]);
    writeA(0, g[0]);
    WAITLGKM0; BAR; CFENCE; SCHEDB;

    #pragma unroll
    for (int u = 0; u < 8; ++u) {
        if (u + 2 <= 7) {
            loadA(u + 2, g[u & 1]);
            issueB(u + 2, (u + 2) % 3);
        }

        const char* Ab = Asb_b + (u & 1) * 8192;
        const char* Bb = Bsb_b + (u % 3) * 16384;
        bf16x8 a[4], b[4];
        #pragma unroll
        for (int mi = 0; mi < 4; ++mi) a[mi] = *(const bf16x8*)(Ab + a_off[mi]);
        #pragma unroll
        for (int ni = 0; ni < 4; ++ni) b[ni] = *(const bf16x8*)(Bb + b_off[ni]);

        #pragma unroll
        for (int mi = 0; mi < 4; ++mi)
            #pragma unroll
            for (int ni = 0; ni < 4; ++ni)
                acc[mi][ni] = __builtin_amdgcn_mfma_f32_16x16x32_bf16(
                    a[mi], b[ni], acc[mi][ni], 0, 0, 0);

        if (u + 1 <= 7) {
            writeA((u + 1) & 1, g[(u + 1) & 1]);
            WAITLGKM0; BAR; CFENCE; SCHEDB;
        }
    }

    // ---- epilogue ----
    float bb[4];
    #pragma unroll
    for (int ni = 0; ni < 4; ++ni) bb[ni] = bias[wc * 64 + ni * 16 + l15];

    if (isV) {
        #pragma unroll
        for (int mi = 0; mi < 4; ++mi)
            #pragma unroll
            for (int rr = 0; rr < 4; ++rr) {
                const int row = row0 + wr * 64 + mi * 16 + l4 * 4 + rr;
                if (row >= M) continue;
                #pragma unroll
                for (int ni = 0; ni < 4; ++ni)
                    v_bf[(size_t)row * 256 + wc * 64 + ni * 16 + l15] =
                        (__bf16)(acc[mi][ni][rr] + bb[ni]);
            }
    } else {
        float we0[4], we1[4];
        #pragma unroll
        for (int ni = 0; ni < 4; ++ni) {
            const int c = wc * 64 + ni * 16 + l15;     // local col 0..255
            we0[ni] = colhalf ? wex[c]       : 0.f;
            we1[ni] = colhalf ? wex[256 + c] : 0.f;
        }
        #pragma unroll
        for (int mi = 0; mi < 4; ++mi)
            #pragma unroll
            for (int rr = 0; rr < 4; ++rr) {
                const int row = row0 + wr * 64 + mi * 16 + l4 * 4 + rr;
                if (row >= M) continue;
                const float e0 = objs[(size_t)row * 2];
                const float e1 = objs[(size_t)row * 2 + 1];
                #pragma unroll
                for (int ni = 0; ni < 4; ++ni) {
                    const int c = wc * 64 + ni * 16 + l15;
                    float v = acc[mi][ni][rr] + bb[ni];
                    if (colhalf) {
                        v += e0 * we0[ni] + e1 * we1[ni];
                        v = fmaxf(v, 0.f);
                    }
                    axyhid[(size_t)row * 512 + colhalf * 256 + c] = v;
                }
            }
    }
}

// ---------------------------------------------------------------------------
// Deep-pipelined bf16 MFMA GEMM, 4-wave 128x128 (verified R8) — small GEMMs.
// ---------------------------------------------------------------------------
template<bool OUTBF16>
__global__ __launch_bounds__(256)
void gemm_dp(const float* __restrict__ A, const __bf16* __restrict__ Wt,
             const float* __restrict__ bias, void* __restrict__ outp,
             int M, int N, int LDA)
{
    __shared__ float4 AsbV[2][512];
    __shared__ float4 BsbV[3][512];
    char* const Asb_b = (char*)AsbV;
    char* const Bsb_b = (char*)BsbV;

    const int tid  = threadIdx.x;
    const int wave = tid >> 6, lane = tid & 63;
    const int wr = wave >> 1, wc = wave & 1;
    const int row0 = blockIdx.y * 128, col0 = blockIdx.x * 128;
    const int l15 = lane & 15, l4 = lane >> 4;

    const int st_row = tid >> 1, st_kh = tid & 1;
    const int gr_cl  = min(row0 + st_row, M - 1);
    const float* Abase = A + (size_t)gr_cl * LDA + st_kh * 16;
    const int asw   = (st_row >> 1) & 3;
    const int a_wo0 = st_row * 64 + ((st_kh * 2)     ^ asw) * 16;
    const int a_wo1 = st_row * 64 + ((st_kh * 2 + 1) ^ asw) * 16;

    int a_off[4], b_off[4];
    #pragma unroll
    for (int mi = 0; mi < 4; ++mi) {
        const int r   = wr * 64 + mi * 16 + l15;
        a_off[mi] = r * 64 + (l4 ^ ((r >> 1) & 3)) * 16;
    }
    #pragma unroll
    for (int ni = 0; ni < 4; ++ni) {
        const int c   = wc * 64 + ni * 16 + l15;
        b_off[ni] = c * 64 + (l4 ^ ((c >> 1) & 3)) * 16;
    }

    const __bf16* bsrc[2];
    #pragma unroll
    for (int i = 0; i < 2; ++i) {
        const int c   = (wave * 2 + i) * 64 + lane;
        const int col = c >> 2, kcp = c & 3;
        const int kc  = kcp ^ ((col >> 1) & 3);
        bsrc[i] = Wt + (size_t)(col0 + col) * 256 + kc * 8;
    }

    auto issueB = [&](int kt, int bbuf) {
        #pragma unroll
        for (int i = 0; i < 2; ++i)
            load_lds16(bsrc[i] + kt * 32, Bsb_b + bbuf * 8192 + (wave * 2 + i) * 1024);
    };
    auto loadA = [&](int kt, float4* g) {
        const float* ga = Abase + kt * 32;
        g[0] = ((const float4*)ga)[0];
        g[1] = ((const float4*)ga)[1];
        g[2] = ((const float4*)ga)[2];
        g[3] = ((const float4*)ga)[3];
    };
    auto writeA = [&](int abuf, const float4* g) {
        bf16x8 c0, c1;
        c0[0] = (__bf16)g[0].x; c0[1] = (__bf16)g[0].y; c0[2] = (__bf16)g[0].z; c0[3] = (__bf16)g[0].w;
        c0[4] = (__bf16)g[1].x; c0[5] = (__bf16)g[1].y; c0[6] = (__bf16)g[1].z; c0[7] = (__bf16)g[1].w;
        c1[0] = (__bf16)g[2].x; c1[1] = (__bf16)g[2].y; c1[2] = (__bf16)g[2].z; c1[3] = (__bf16)g[2].w;
        c1[4] = (__bf16)g[3].x; c1[5] = (__bf16)g[3].y; c1[6] = (__bf16)g[3].z; c1[7] = (__bf16)g[3].w;
        *(bf16x8*)(Asb_b + abuf * 8192 + a_wo0) = c0;
        *(bf16x8*)(Asb_b + abuf * 8192 + a_wo1) = c1;
    };

    f32x4 acc[4][4] = {};
    float4 g[2][4];

    issueB(0, 0);
    loadA(0, g[0]);
    issueB(1, 1);
    loadA(1, g[1]);
    writeA(0, g[0]);
    WAITLGKM0; BAR; CFENCE; SCHEDB;

    #pragma unroll
    for (int u = 0; u < 8; ++u) {
        if (u + 2 <= 7) {
            loadA(u + 2, g[u & 1]);
            issueB(u + 2, (u + 2) % 3);
        }

        const char* Ab = Asb_b + (u & 1) * 8192;
        const char* Bb = Bsb_b + (u % 3) * 8192;
        bf16x8 a[4], b[4];
        #pragma unroll
        for (int mi = 0; mi < 4; ++mi) a[mi] = *(const bf16x8*)(Ab + a_off[mi]);
        #pragma unroll
        for (int ni = 0; ni < 4; ++ni) b[ni] = *(const bf16x8*)(Bb + b_off[ni]);

        #pragma unroll
        for (int mi = 0; mi < 4; ++mi)
            #pragma unroll
            for (int ni = 0; ni < 4; ++ni)
                acc[mi][ni] = __builtin_amdgcn_mfma_f32_16x16x32_bf16(
                    a[mi], b[ni], acc[mi][ni], 0, 0, 0);

        if (u + 1 <= 7) {
            writeA((u + 1) & 1, g[(u + 1) & 1]);
            WAITLGKM0; BAR; CFENCE; SCHEDB;
        }
    }

    float bb[4];
    #pragma unroll
    for (int ni = 0; ni < 4; ++ni) bb[ni] = bias[col0 + wc * 64 + ni * 16 + l15];
    #pragma unroll
    for (int mi = 0; mi < 4; ++mi) {
        #pragma unroll
        for (int rr = 0; rr < 4; ++rr) {
            const int row = row0 + wr * 64 + mi * 16 + l4 * 4 + rr;
            if (row >= M) continue;
            #pragma unroll
            for (int ni = 0; ni < 4; ++ni) {
                const float v = acc[mi][ni][rr] + bb[ni];
                const int colb = col0 + wc * 64 + ni * 16 + l15;
                if (OUTBF16) ((__bf16*)outp)[(size_t)row * N + colb] = (__bf16)v;
                else         ((float*)outp)[(size_t)row * N + colb]  = v;
            }
        }
    }
}

// ---------------------------------------------------------------------------
// Fused: softmax (spec cancels) + locations + VECTORIZED bilinear sampling.
// ---------------------------------------------------------------------------
__global__ __launch_bounds__(256)
void attn_sample_kernel(const float* __restrict__ axyhid,
                        const float* __restrict__ refp, const float* __restrict__ objs,
                        const float* __restrict__ off, const __bf16* __restrict__ v,
                        float* __restrict__ agg)
{
    const int bq = blockIdx.x;
    const int b  = bq / Q_;
    const int tid = threadIdx.x;

    __shared__ float sm[128];
    __shared__ float sa[128];
    __shared__ float sl[256];

    if (tid < 128)
        sm[tid] = axyhid[(size_t)bq * 512 + tid] * axyhid[(size_t)bq * 512 + 128 + tid];
    __syncthreads();

    if (tid < 128) {
        const int hh = tid >> 4;
        float mx = -1e30f;
        #pragma unroll
        for (int i = 0; i < 16; ++i) mx = fmaxf(mx, sm[hh * 16 + i]);
        float s = 0.f;
        #pragma unroll
        for (int i = 0; i < 16; ++i) s += __expf(sm[hh * 16 + i] - mx);
        sa[tid] = __expf(sm[tid] - mx) / s;

        const int l = (tid >> 2) & 3;
        const float os0 = objs[(size_t)bq * 2], os1 = objs[(size_t)bq * 2 + 1];
        const float r0 = refp[((size_t)bq * 4 + l) * 2];
        const float r1 = refp[((size_t)bq * 4 + l) * 2 + 1];
        const float o0 = off[(size_t)bq * 256 + tid * 2]     * os0;
        const float o1 = off[(size_t)bq * 256 + tid * 2 + 1] * os1;
        sl[tid * 2]     = fminf(fmaxf(r0 + o0, 0.f), 1.f);
        sl[tid * 2 + 1] = fminf(fmaxf(r1 + o1, 0.f), 1.f);
    }
    __syncthreads();

    const int h = tid >> 5, lane32 = tid & 31;
    const int sp = lane32 >> 2, cq = lane32 & 3;
    const int chbase = h * 32 + cq * 8;
    const __bf16* vb = v + (size_t)b * S_ * 256;

    float acc8[8] = {};

    #pragma unroll
    for (int gidx = 0; gidx < 2; ++gidx) {
        const int lp  = gidx * 8 + sp;
        const int li  = h * 16 + lp;
        const int lvl = lp >> 2;
        const int Wl = (lvl == 0) ? 100 : (lvl == 1) ? 50 : (lvl == 2) ? 25 : 13;
        const int Hl = Wl;
        const int st = (lvl == 0) ? 0 : (lvl == 1) ? 10000 : (lvl == 2) ? 12500 : 13125;

        const float a  = sa[li];
        const float lx = sl[li * 2], ly = sl[li * 2 + 1];
        const float x = lx * (float)Wl - 0.5f;
        const float y = ly * (float)Hl - 0.5f;
        const float x0f = floorf(x), y0f = floorf(y);
        const float fx = x - x0f, fy = y - y0f;
        const int x0 = (int)x0f, y0 = (int)y0f;

        #pragma unroll
        for (int c = 0; c < 4; ++c) {
            const int dx = c & 1, dy = c >> 1;
            const int xi = x0 + dx, yi = y0 + dy;
            const float wgt = (dx ? fx : 1.f - fx) * (dy ? fy : 1.f - fy);
            const bool valid = (xi >= 0) & (xi < Wl) & (yi >= 0) & (yi < Hl);
            const int idx = min(max(yi, 0), Hl - 1) * Wl + min(max(xi, 0), Wl - 1);
            const float wa = valid ? a * wgt : 0.f;
            const bf16x8 gv = *(const bf16x8*)(vb + (size_t)(st + idx) * 256 + chbase);
            #pragma unroll
            for (int j = 0; j < 8; ++j) acc8[j] += wa * (float)gv[j];
        }
    }

    #pragma unroll
    for (int m = 4; m <= 16; m <<= 1)
        #pragma unroll
        for (int j = 0; j < 8; ++j)
            acc8[j] += __shfl_xor(acc8[j], m);

    if (sp == 0) {
        #pragma unroll
        for (int j = 0; j < 8; ++j)
            agg[(size_t)bq * 256 + chbase + j] = acc8[j];
    }
}

// ---------------------------------------------------------------------------
extern "C" void kernel_launch(void* const* d_in, const int* in_sizes, int n_in,
                              void* d_out, int out_size, void* d_ws, size_t ws_size,
                              hipStream_t stream)
{
    const float* query = (const float*)d_in[0];
    const float* refp  = (const float*)d_in[1];
    const float* x_in  = (const float*)d_in[2];
    const float* objs  = (const float*)d_in[3];
    const float* w_q    = (const float*)d_in[6];
    const float* b_q    = (const float*)d_in[7];
    const float* w_v    = (const float*)d_in[8];
    const float* b_v    = (const float*)d_in[9];
    const float* w_o    = (const float*)d_in[10];
    const float* b_o    = (const float*)d_in[11];
    const float* w_off1 = (const float*)d_in[12];
    const float* b_off1 = (const float*)d_in[13];
    const float* w_off2 = (const float*)d_in[14];
    const float* b_off2 = (const float*)d_in[15];
    const float* w_ax   = (const float*)d_in[16];
    const float* b_ax   = (const float*)d_in[17];
    const float* w_ay   = (const float*)d_in[18];
    const float* b_ay   = (const float*)d_in[19];

    float* ws = (float*)d_ws;
    float* axyhid_ws = ws;                               // BQ*512 f32
    float* off_ws    = axyhid_ws + (size_t)BQ * 512;     // BQ*256 f32
    float* agg_ws    = off_ws    + (size_t)BQ * 256;     // BQ*256 f32
    float* bcomb_ws  = agg_ws    + (size_t)BQ * 256;     // 512 f32
    __bf16* v_bf    = (__bf16*)(bcomb_ws + 512);         // BS*256 bf16
    __bf16* wt_v    = v_bf    + (size_t)BS * 256;
    __bf16* wt_o    = wt_v    + 256 * 256;
    __bf16* wt_off2 = wt_o    + 256 * 256;
    __bf16* wt_cat  = wt_off2 + 256 * 256;               // 512*256
    __bf16* wcomb   = wt_cat  + 512 * 256;               // 512*256

    const dim3 blk(256);

    // weight prep
    transpose_all<<<320, blk, 0, stream>>>(w_v, w_o, w_off1, w_off2, w_ax, w_ay,
                                           wt_v, wt_o, wt_off2, wt_cat);
    combine2<<<10, blk, 0, stream>>>(wt_cat, w_q, b_q, b_ax, b_ay, b_off1,
                                     wcomb, bcomb_ws);

    // fused: v-GEMM (831 blocks) + axyhid GEMM (114 blocks)
    main_fused<<<NVB + 114, dim3(512), 0, stream>>>(
        x_in, wt_v, b_v, v_bf,
        query, wcomb, bcomb_ws, objs, w_off1 + 256 * 256, axyhid_ws);

    // offsets = hid @ w_off2 + b_off2 -> f32
    gemm_dp<false><<<dim3(2, (BQ + 127) / 128), blk, 0, stream>>>(
        axyhid_ws + 256, wt_off2, b_off2, off_ws, BQ, 256, 512);

    // fused softmax/locs/sampling (vectorized gathers)
    attn_sample_kernel<<<BQ, blk, 0, stream>>>(axyhid_ws, refp, objs, off_ws,
                                               v_bf, agg_ws);

    // out = agg @ w_o + b_o -> f32
    gemm_dp<false><<<dim3(2, (BQ + 127) / 128), blk, 0, stream>>>(
        agg_ws, wt_o, b_o, (float*)d_out, BQ, 256, 256);
}